// Round 17
// baseline (98.180 us; speedup 1.0000x reference)
//
#include <hip/hip_runtime.h>

typedef float  f32x4  __attribute__((ext_vector_type(4)));
typedef float  f32x16 __attribute__((ext_vector_type(16)));
typedef __bf16 bf16x8 __attribute__((ext_vector_type(8)));
typedef short  s16x8  __attribute__((ext_vector_type(8)));
typedef short  s16x4  __attribute__((ext_vector_type(4)));
typedef unsigned int u32x4 __attribute__((ext_vector_type(4)));

static __device__ __forceinline__ unsigned short f2bf(float f) {
  return __builtin_bit_cast(unsigned short, (__bf16)f);
}
static __device__ __forceinline__ bf16x8 bc8(s16x8 v) {
  return __builtin_bit_cast(bf16x8, v);
}
static __device__ __forceinline__ f32x16 mfma32(bf16x8 a, bf16x8 b, f32x16 c) {
  return __builtin_amdgcn_mfma_f32_32x32x16_bf16(a, b, c, 0, 0, 0);
}
static __device__ __forceinline__ f32x4 mfma16(bf16x8 a, bf16x8 b, f32x4 c) {
  return __builtin_amdgcn_mfma_f32_16x16x32_bf16(a, b, c, 0, 0, 0);
}

// async global->LDS, 16B per lane.
static __device__ __forceinline__ void gl2lds16(const unsigned short* g, unsigned short* l) {
  __builtin_amdgcn_global_load_lds(
      (const __attribute__((address_space(1))) unsigned int*)g,
      (__attribute__((address_space(3))) unsigned int*)l, 16, 0, 0);
}

// counted-vmcnt sync: wait until <= N vector-mem instrs outstanding, then barrier.
#define GSYNC(NSTR)                                          \
  do {                                                       \
    __builtin_amdgcn_sched_barrier(0);                       \
    asm volatile("s_waitcnt vmcnt(" NSTR ")" ::: "memory");  \
    __builtin_amdgcn_s_barrier();                            \
    __builtin_amdgcn_sched_barrier(0);                       \
  } while (0)

// ---------------- fused prep: cast x (blocks 0..2047) + transpose W (2048..3071) ----
__global__ void prep_k(const float* __restrict__ x, unsigned short* __restrict__ xb,
                       const float* __restrict__ W0, const float* __restrict__ W1,
                       const float* __restrict__ W2, const float* __restrict__ W3,
                       unsigned short* __restrict__ wtb) {
  __shared__ unsigned short tl[64][72];
  const int bid = blockIdx.x;
  const int t = threadIdx.x;
  if (bid < 2048) {
    int i = (bid * 256 + t) * 8;
    float4 a = *(const float4*)(x + i);
    float4 b = *(const float4*)(x + i + 4);
    s16x8 o;
    o[0] = (short)f2bf(a.x); o[1] = (short)f2bf(a.y);
    o[2] = (short)f2bf(a.z); o[3] = (short)f2bf(a.w);
    o[4] = (short)f2bf(b.x); o[5] = (short)f2bf(b.y);
    o[6] = (short)f2bf(b.z); o[7] = (short)f2bf(b.w);
    *(s16x8*)(xb + i) = o;
    return;
  }
  const int rid = bid - 2048;
  const int z = rid >> 8, rem = rid & 255;
  const float* W = z == 0 ? W0 : z == 1 ? W1 : z == 2 ? W2 : W3;
  unsigned short* out = wtb + (size_t)z * 1048576;
  const int nt = (rem & 15) * 64, kt = (rem >> 4) * 64;
  const int row = t >> 2, seg = t & 3;
  const float* src = W + (kt + row) * 1024 + nt + seg * 16;
#pragma unroll
  for (int q = 0; q < 4; ++q) {
    float4 v = *(const float4*)(src + q * 4);
    tl[seg * 16 + q * 4 + 0][row] = f2bf(v.x);
    tl[seg * 16 + q * 4 + 1][row] = f2bf(v.y);
    tl[seg * 16 + q * 4 + 2][row] = f2bf(v.z);
    tl[seg * 16 + q * 4 + 3][row] = f2bf(v.w);
  }
  __syncthreads();
  unsigned short* dst = out + (nt + row) * 1024 + kt + seg * 16;
  *(s16x8*)dst       = *(const s16x8*)&tl[row][seg * 16];
  *(s16x8*)(dst + 8) = *(const s16x8*)&tl[row][seg * 16 + 8];
}

static __device__ __forceinline__ int trans_ix(int m, int n) {
  int b = m >> 11, tt = m & 2047, h = n >> 6, dh = n & 63;
  return ((b << 4) + h) * 131072 + tt * 64 + dh;
}

// ======== fused QKV GEMM v6: r16 main loop + LDS-transposed coalesced vT store ====
// 256x192 tile, BK=64, grid 256 (1 block/CU), single-boundary phases.
// Epilogue change: vT bf16 goes through an LDS slab (cols x 264-short rows) and is
// streamed out as 128B-contiguous t-runs (was: 8B/lane at 4KB stride = scatter).
__global__ __launch_bounds__(512, 2) void gemm_qkv_k(const unsigned short* __restrict__ A,
                                                     const unsigned short* __restrict__ BT,
                                                     const float* __restrict__ b0,
                                                     const float* __restrict__ b1,
                                                     const float* __restrict__ b2,
                                                     float* __restrict__ outF,
                                                     unsigned short* __restrict__ oq,
                                                     unsigned short* __restrict__ ok,
                                                     unsigned short* __restrict__ ovT) {
  extern __shared__ unsigned short lds[];
  const int t = threadIdx.x;
  const int lane = t & 63, ln = lane & 15, g = lane >> 4;
  const int w = t >> 6, wm = w >> 2, wn = w & 3;  // 2 (M) x 4 (N)
  const unsigned wgid = blockIdx.x;
  const unsigned swz = (wgid & 7) * 32 + (wgid >> 3);  // XCD-contiguous (256%8==0)
  const int by = swz & 15, bx = swz >> 4;              // 2 B-panels per XCD
  const int bm0 = by * 256, bn0 = bx * 192;

  const int brow = t >> 3;
  const unsigned short* bSrcBase =
      BT + (size_t)(bn0 + brow) * 1024 + (((t & 7) ^ (brow & 7)) * 8);
  const int arow = t >> 2;
  const unsigned short* aSrcBase =
      A + (size_t)(bm0 + arow) * 1024 + (((t & 3) ^ ((t >> 3) & 3)) * 8);

  auto issueTile = [&](int T, int buf) {  // 7 loads: B0,B1,B2, A(h0,a0..1), A(h1,a0..1)
    const int kt = T * 64;
#pragma unroll
    for (int j = 0; j < 3; ++j)
      gl2lds16(bSrcBase + (size_t)j * 65536 + kt, &lds[buf * 28672 + j * 4096 + t * 8]);
#pragma unroll
    for (int H = 0; H < 2; ++H)
#pragma unroll
      for (int a = 0; a < 2; ++a)
        gl2lds16(aSrcBase + (size_t)a * 131072 + kt + H * 32,
                 &lds[buf * 28672 + 12288 + H * 8192 + a * 4096 + t * 8]);
  };
  auto ldA = [&](int buf, int H, int mf) -> bf16x8 {
    const int row = wm * 128 + mf * 16 + ln;
    const int sp = g ^ ((row >> 1) & 3);
    return bc8(*(const s16x8*)&lds[buf * 28672 + 12288 + H * 8192 + row * 32 + sp * 8]);
  };
  auto ldB = [&](int buf, int H, int nf) -> bf16x8 {
    const int row = wn * 48 + nf * 16 + ln;
    const int sp = (H * 4 + g) ^ (row & 7);
    return bc8(*(const s16x8*)&lds[buf * 28672 + row * 64 + sp * 8]);
  };

  f32x4 acc[8][3] = {};
  issueTile(0, 0);
  issueTile(1, 1);

  for (int ti = 0; ti < 16; ++ti) {
    const int buf = ti & 1;
    if (ti < 15) GSYNC("7"); else GSYNC("0");

    bf16x8 af0[8], bf0[3], af1[8], bf1[3];
#pragma unroll
    for (int mf = 0; mf < 8; ++mf) af0[mf] = ldA(buf, 0, mf);
#pragma unroll
    for (int nf = 0; nf < 3; ++nf) bf0[nf] = ldB(buf, 0, nf);
#pragma unroll
    for (int mf = 0; mf < 8; ++mf) af1[mf] = ldA(buf, 1, mf);
#pragma unroll
    for (int nf = 0; nf < 3; ++nf) bf1[nf] = ldB(buf, 1, nf);

    asm volatile("s_waitcnt lgkmcnt(11)" ::: "memory");
    __builtin_amdgcn_sched_barrier(0);
    __builtin_amdgcn_s_setprio(1);
#pragma unroll
    for (int mf = 0; mf < 8; ++mf)
#pragma unroll
      for (int nf = 0; nf < 3; ++nf) acc[mf][nf] = mfma16(af0[mf], bf0[nf], acc[mf][nf]);
    __builtin_amdgcn_s_setprio(0);

    asm volatile("s_waitcnt lgkmcnt(0)" ::: "memory");
    __builtin_amdgcn_sched_barrier(0);
    __builtin_amdgcn_s_barrier();
    __builtin_amdgcn_sched_barrier(0);
    if (ti + 2 < 16) issueTile(ti + 2, buf);

    __builtin_amdgcn_s_setprio(1);
#pragma unroll
    for (int mf = 0; mf < 8; ++mf)
#pragma unroll
      for (int nf = 0; nf < 3; ++nf) acc[mf][nf] = mfma16(af1[mf], bf1[nf], acc[mf][nf]);
    __builtin_amdgcn_s_setprio(0);
  }

  // ---- epilogue ----
  // v-column geometry: block n-range [bn0, bn0+192); v-cols are n >= 2048.
  int cv0 = 2048 - bn0;
  cv0 = cv0 < 0 ? 0 : cv0;
  const int vcols = cv0 >= 192 ? 0 : 192 - cv0;
  short* slab = (short*)lds;  // [vcol][264 shorts]; free after final GSYNC(0)

#pragma unroll
  for (int nf = 0; nf < 3; ++nf) {
    const int n = bn0 + wn * 48 + nf * 16 + ln;
    const int n1 = n & 1023;
    const float* bp = n < 1024 ? b0 : (n < 2048 ? b1 : b2);
    const float bias = bp[n1];
    if (n < 1024) {
#pragma unroll
      for (int mf = 0; mf < 8; ++mf)
#pragma unroll
        for (int r = 0; r < 4; ++r) {
          const int m = bm0 + wm * 128 + mf * 16 + g * 4 + r;
          oq[trans_ix(m, n1)] = f2bf((acc[mf][nf][r] + bias) * 0.18033688f);  // 0.125*log2e
        }
    } else if (n < 2048) {
#pragma unroll
      for (int mf = 0; mf < 8; ++mf)
#pragma unroll
        for (int r = 0; r < 4; ++r) {
          const int m = bm0 + wm * 128 + mf * 16 + g * 4 + r;
          const float v = acc[mf][nf][r] + bias;
          const int ix = trans_ix(m, n1);
          ok[ix] = f2bf(v);
          outF[4194304 + ix] = v;
        }
    } else {  // V: fp32 direct (64B segs); bf16 -> LDS slab for coalesced vT store
      const int vcol = (wn * 48 + nf * 16 + ln) - cv0;  // >= 0 for v-cols
#pragma unroll
      for (int mf = 0; mf < 8; ++mf) {
        const int m0l = wm * 128 + mf * 16 + g * 4;
        s16x4 pv;
#pragma unroll
        for (int r = 0; r < 4; ++r) {
          const float v = acc[mf][nf][r] + bias;
          outF[8388608 + trans_ix(bm0 + m0l + r, n1)] = v;
          pv[r] = (short)f2bf(v);
        }
        *(s16x4*)(slab + vcol * 264 + m0l) = pv;
      }
    }
  }

  if (vcols > 0) {  // stream slab out as contiguous 128B t-runs
    __syncthreads();
    const int bb2 = bm0 >> 11, tt0 = bm0 & 2047;
    const int tasks = vcols * 4;  // (vcol, 64-row chunk)
#pragma unroll
    for (int it = 0; it < 2; ++it) {
      const int idx = t + 512 * it;
      if (idx < tasks) {
        const int vc = idx >> 2, rch = (idx & 3) * 64;
        const int n1v = bn0 + cv0 + vc - 2048;
        const int hh = n1v >> 6, dh = n1v & 63;
        unsigned short* dst =
            ovT + (size_t)((bb2 << 4) + hh) * 131072 + (size_t)dh * 2048 + tt0 + rch;
        const short* srcS = slab + vc * 264 + rch;
#pragma unroll
        for (int j = 0; j < 8; ++j)
          *(s16x8*)(dst + j * 8) = *(const s16x8*)(srcS + j * 8);
      }
    }
  }
}

// ======== O-proj GEMM (unchanged r13): BM=64, BN=128, BK=64, counted vmcnt ========
__global__ __launch_bounds__(512, 4) void gemm_o_k(const unsigned short* __restrict__ A,
                                                   const unsigned short* __restrict__ BT,
                                                   const float* __restrict__ b0,
                                                   float* __restrict__ outF) {
  extern __shared__ unsigned short lds[];
  const int t = threadIdx.x;
  const int lane = t & 63, ln = lane & 15, g = lane >> 4;
  const int w = t >> 6, wm = w >> 2, wn = w & 3;
  const unsigned wgid = blockIdx.x;
  const unsigned swz = (wgid & 7) * 64 + (wgid >> 3);
  const int bx = swz & 7, by = swz >> 3;
  const int bm0 = by * 64, bn0 = bx * 128;

  const int row = t >> 3;
  const int scol = (t & 7) ^ (row & 7);
  const unsigned short* aSrc = A + (size_t)(bm0 + row) * 1024 + scol * 8;
  const unsigned short* bSrc0 = BT + (size_t)(bn0 + row) * 1024 + scol * 8;
  const unsigned short* bSrc1 = BT + (size_t)(bn0 + 64 + row) * 1024 + scol * 8;

  auto issue3 = [&](int buf, int ti) {
    const int kt = ti * 64;
    gl2lds16(aSrc + kt, &lds[buf * 12288 + t * 8]);
    gl2lds16(bSrc0 + kt, &lds[buf * 12288 + 4096 + t * 8]);
    gl2lds16(bSrc1 + kt, &lds[buf * 12288 + 8192 + t * 8]);
  };
  auto ldA = [&](int buf, int H, int mf) -> bf16x8 {
    const int r = wm * 32 + mf * 16 + ln;
    const int sp = (H * 4 + g) ^ (r & 7);
    return bc8(*(const s16x8*)&lds[buf * 12288 + r * 64 + sp * 8]);
  };
  auto ldB = [&](int buf, int H, int nf) -> bf16x8 {
    const int r = wn * 32 + nf * 16 + ln;
    const int j = r >> 6, rl = r & 63;
    const int sp = (H * 4 + g) ^ (rl & 7);
    return bc8(*(const s16x8*)&lds[buf * 12288 + 4096 + j * 4096 + rl * 64 + sp * 8]);
  };

  f32x4 acc[2][2] = {};
  issue3(0, 0);
  issue3(1, 1);

  for (int i = 0; i < 16; ++i) {
    const int buf = i & 1;
    if (i < 15) GSYNC("3"); else GSYNC("0");
    bf16x8 a0[2], a1[2], bq0[2], bq1[2];
#pragma unroll
    for (int mf = 0; mf < 2; ++mf) { a0[mf] = ldA(buf, 0, mf); a1[mf] = ldA(buf, 1, mf); }
#pragma unroll
    for (int nf = 0; nf < 2; ++nf) { bq0[nf] = ldB(buf, 0, nf); bq1[nf] = ldB(buf, 1, nf); }
    asm volatile("s_waitcnt lgkmcnt(0)" ::: "memory");
    __builtin_amdgcn_sched_barrier(0);
    __builtin_amdgcn_s_barrier();
    __builtin_amdgcn_sched_barrier(0);
    if (i + 2 < 16) issue3(buf, i + 2);
    __builtin_amdgcn_s_setprio(1);
#pragma unroll
    for (int mf = 0; mf < 2; ++mf)
#pragma unroll
      for (int nf = 0; nf < 2; ++nf) {
        acc[mf][nf] = mfma16(a0[mf], bq0[nf], acc[mf][nf]);
        acc[mf][nf] = mfma16(a1[mf], bq1[nf], acc[mf][nf]);
      }
    __builtin_amdgcn_s_setprio(0);
  }

#pragma unroll
  for (int nf = 0; nf < 2; ++nf) {
    const int n = bn0 + wn * 32 + nf * 16 + ln;
    const float bias = b0[n];
#pragma unroll
    for (int mf = 0; mf < 2; ++mf)
#pragma unroll
      for (int r = 0; r < 4; ++r) {
        const int m = bm0 + wm * 32 + mf * 16 + g * 4 + r;
        outF[(size_t)m * 1024 + n] = acc[mf][nf][r] + bias;
      }
  }
}

// ---------------- flash attention v10 (unchanged r13) ----------------
__global__ __launch_bounds__(768) void attn_k(const unsigned short* __restrict__ qb,
                                              const unsigned short* __restrict__ kb,
                                              const unsigned short* __restrict__ vbT,
                                              unsigned short* __restrict__ ob) {
  extern __shared__ s16x8 kvS[];  // 3 grp x 3 buf x (K 512 | V 512) = 9216 vec = 144KB
  const int t = threadIdx.x;
  const int lane = t & 63, l31 = lane & 31, h5 = lane >> 5;
  const int w = t >> 6, grp = w >> 2, qw = w & 3;  // w 0..11
  const unsigned wg = blockIdx.x;
  const int x = wg & 7, r_ = wg >> 3;
  const int bh = x + 8 * (r_ >> 3);
  const int p = r_ & 7;
  const int b = bh >> 4, h = bh & 15;
  const unsigned short* Qp = qb + (size_t)bh * 131072;
  const unsigned short* Kp = kb + (size_t)bh * 131072;
  const unsigned short* Vp = vbT + (size_t)bh * 131072;

  const int e0 = t & 255;
  const int kr0 = e0 >> 3;
  const int kcol = (e0 & 7) ^ (kr0 & 7);
  const unsigned short* kSrc = Kp + (size_t)kr0 * 64 + kcol * 8;
  const unsigned short* vSrc = Vp + (size_t)kr0 * 2048 + kcol * 8;
  s16x8* gB = &kvS[grp * 3072];

  s16x8 onesv;
#pragma unroll
  for (int z = 0; z < 8; ++z) onesv[z] = (short)0x3F80;  // bf16 1.0
  const bf16x8 onesf = bc8(onesv);

  float* sc = (float*)kvS;
  const int slot = qw * 64 + lane;

  for (int half = 0; half < 2; ++half) {
    const int qblk = half == 0 ? p : 15 - p;
    const int q0 = qblk * 128;
    const int N64 = 2 * qblk + 2;
    const int base = N64 / 3, rem3 = N64 % 3;
    const int cnt = base + (grp < rem3 ? 1 : 0);
    const int start = grp * base + (grp < rem3 ? grp : rem3);
    const int NP = base + (rem3 ? 1 : 0);
    const int qg = q0 + qw * 32 + l31;

    __syncthreads();

    bf16x8 qf[4];
#pragma unroll
    for (int m = 0; m < 4; ++m)
      qf[m] = bc8(*(const s16x8*)(Qp + (size_t)qg * 64 + 16 * m + 8 * h5));

    auto issue = [&](int T, int buf) {
      const int kv0 = T * 64;
      unsigned short* kd = (unsigned short*)&gB[buf * 1024];
      unsigned short* vd = (unsigned short*)&gB[buf * 1024 + 512];
      const unsigned short* ks = kSrc + (size_t)kv0 * 64;
      const unsigned short* vs = vSrc + kv0;
      gl2lds16(ks,         kd + e0 * 8);
      gl2lds16(ks + 2048,  kd + (e0 + 256) * 8);
      gl2lds16(vs,         vd + e0 * 8);
      gl2lds16(vs + 65536, vd + (e0 + 256) * 8);
    };

    if (cnt > 0) issue(start, 0);
    if (cnt > 1) issue(start + 1, 1);

    f32x16 o0 = {}, o1 = {}, lsum = {};

    for (int i = 0; i < NP; ++i) {
      __builtin_amdgcn_sched_barrier(0);
      if (i + 1 < cnt) asm volatile("s_waitcnt vmcnt(4)" ::: "memory");
      else             asm volatile("s_waitcnt vmcnt(0)" ::: "memory");
      __builtin_amdgcn_s_barrier();
      __builtin_amdgcn_sched_barrier(0);
      if (i + 2 < cnt) issue(start + i + 2, (i + 2) % 3);
      const int T = start + i;
      const int kv0 = T * 64;
      const bool active = (i < cnt) && (kv0 <= q0 + qw * 32 + 31);
      if (active) {
        const int buf = i % 3;
        const s16x8* kb_ = &gB[buf * 1024];
        const s16x8* vb2 = &gB[buf * 1024 + 512];
        f32x16 s0 = {}, s1 = {};
        __builtin_amdgcn_s_setprio(1);
#pragma unroll
        for (int m = 0; m < 4; ++m) {
          const int sl = 2 * m + h5;
          bf16x8 a0 = bc8(kb_[l31 * 8 + (sl ^ (l31 & 7))]);
          bf16x8 a1 = bc8(kb_[(l31 + 32) * 8 + (sl ^ (l31 & 7))]);
          s0 = mfma32(a0, qf[m], s0);
          s1 = mfma32(a1, qf[m], s1);
        }
        __builtin_amdgcn_s_setprio(0);
        if (kv0 + 63 > q0 + qw * 32) {
#pragma unroll
          for (int r = 0; r < 16; ++r) {
            const int kvr = kv0 + (r & 3) + 8 * (r >> 2) + 4 * h5;
            if (kvr > qg) s0[r] = -1e30f;
            if (kvr + 32 > qg) s1[r] = -1e30f;
          }
        }
#pragma unroll
        for (int r = 0; r < 16; ++r) {
          s0[r] = __builtin_amdgcn_exp2f(s0[r]);
          s1[r] = __builtin_amdgcn_exp2f(s1[r]);
        }
        unsigned og[2][4][2];
#pragma unroll
        for (int gg = 0; gg < 4; ++gg) {
          asm("v_cvt_pk_bf16_f32 %0, %1, %2" : "=v"(og[0][gg][0]) : "v"(s0[4 * gg]),     "v"(s0[4 * gg + 1]));
          asm("v_cvt_pk_bf16_f32 %0, %1, %2" : "=v"(og[0][gg][1]) : "v"(s0[4 * gg + 2]), "v"(s0[4 * gg + 3]));
          asm("v_cvt_pk_bf16_f32 %0, %1, %2" : "=v"(og[1][gg][0]) : "v"(s1[4 * gg]),     "v"(s1[4 * gg + 1]));
          asm("v_cvt_pk_bf16_f32 %0, %1, %2" : "=v"(og[1][gg][1]) : "v"(s1[4 * gg + 2]), "v"(s1[4 * gg + 3]));
        }
        bf16x8 pf[4];
#pragma unroll
        for (int mp = 0; mp < 4; ++mp) {
          const int tau = mp >> 1, lc = mp & 1;
          unsigned a0 = og[tau][2 * lc][0], bq0 = og[tau][2 * lc + 1][0];
          unsigned a1 = og[tau][2 * lc][1], bq1 = og[tau][2 * lc + 1][1];
          asm volatile("v_permlane32_swap_b32 %0, %1" : "+v"(a0), "+v"(bq0));
          asm volatile("v_permlane32_swap_b32 %0, %1" : "+v"(a1), "+v"(bq1));
          u32x4 fw; fw[0] = a0; fw[1] = a1; fw[2] = bq0; fw[3] = bq1;
          pf[mp] = __builtin_bit_cast(bf16x8, fw);
        }
        __builtin_amdgcn_s_setprio(1);
#pragma unroll
        for (int mp = 0; mp < 4; ++mp) {
          const int sl = 2 * mp + h5;
          bf16x8 va0 = bc8(vb2[l31 * 8 + (sl ^ (l31 & 7))]);
          bf16x8 va1 = bc8(vb2[(l31 + 32) * 8 + (sl ^ (l31 & 7))]);
          o0 = mfma32(va0, pf[mp], o0);
          o1 = mfma32(va1, pf[mp], o1);
          lsum = mfma32(onesf, pf[mp], lsum);
        }
        __builtin_amdgcn_s_setprio(0);
      }
    }

    __syncthreads();
    if (grp > 0) {
      float* dst = sc + (size_t)(grp - 1) * 8704 + (size_t)slot * 34;
#pragma unroll
      for (int r = 0; r < 8; ++r) {
        *(float2*)(dst + 2 * r)      = make_float2(o0[2 * r], o0[2 * r + 1]);
        *(float2*)(dst + 16 + 2 * r) = make_float2(o1[2 * r], o1[2 * r + 1]);
      }
      dst[32] = lsum[0];
    }
    __syncthreads();
    if (grp == 0) {
      const float* p0 = sc + (size_t)slot * 34;
      const float* p1 = p0 + 8704;
      const float inv = 1.0f / (lsum[0] + p0[32] + p1[32]);
      unsigned short* orow = ob + (size_t)(b * 2048 + qg) * 1024 + h * 64;
#pragma unroll
      for (int rq = 0; rq < 4; ++rq) {
        s16x4 ov0, ov1;
#pragma unroll
        for (int e = 0; e < 4; ++e) {
          const int ei = 4 * rq + e;
          ov0[e] = (short)f2bf((o0[ei] + p0[ei] + p1[ei]) * inv);
          ov1[e] = (short)f2bf((o1[ei] + p0[16 + ei] + p1[16 + ei]) * inv);
        }
        *(s16x4*)(orow + 8 * rq + 4 * h5)      = ov0;
        *(s16x4*)(orow + 32 + 8 * rq + 4 * h5) = ov1;
      }
    }
  }
}

extern "C" void kernel_launch(void* const* d_in, const int* in_sizes, int n_in,
                              void* d_out, int out_size, void* d_ws, size_t ws_size,
                              hipStream_t stream) {
  (void)in_sizes; (void)n_in; (void)out_size; (void)ws_size;
  const float* x  = (const float*)d_in[0];
  const float* Wq = (const float*)d_in[1];
  const float* bq = (const float*)d_in[2];
  const float* Wk = (const float*)d_in[3];
  const float* bk = (const float*)d_in[4];
  const float* Wv = (const float*)d_in[5];
  const float* bv = (const float*)d_in[6];
  const float* Wo = (const float*)d_in[7];
  const float* bo = (const float*)d_in[8];
  float* out = (float*)d_out;

  unsigned short* ws  = (unsigned short*)d_ws;
  unsigned short* xb  = ws;
  unsigned short* wtb = ws + 4194304;
  unsigned short* qbuf = ws + 8388608;
  unsigned short* kbuf = qbuf + 4194304;
  unsigned short* vbuf = kbuf + 4194304;   // holds V TRANSPOSED [bh][dh][t]
  unsigned short* ab   = vbuf + 4194304;

  prep_k<<<3072, 256, 0, stream>>>(x, xb, Wq, Wk, Wv, Wo, wtb);
  gemm_qkv_k<<<256, 512, 114688, stream>>>(xb, wtb, bq, bk, bv, out, qbuf, kbuf, vbuf);
  attn_k<<<256, 768, 147456, stream>>>(qbuf, kbuf, vbuf, ab);
  gemm_o_k<<<512, 512, 49152, stream>>>(ab, wtb + 3145728, bo, out);
}

// Round 18
// 93.869 us; speedup vs baseline: 1.0459x; 1.0459x over previous
//
#include <hip/hip_runtime.h>

typedef float  f32x4  __attribute__((ext_vector_type(4)));
typedef float  f32x16 __attribute__((ext_vector_type(16)));
typedef __bf16 bf16x8 __attribute__((ext_vector_type(8)));
typedef short  s16x8  __attribute__((ext_vector_type(8)));
typedef short  s16x4  __attribute__((ext_vector_type(4)));
typedef unsigned int u32x4 __attribute__((ext_vector_type(4)));

static __device__ __forceinline__ unsigned short f2bf(float f) {
  return __builtin_bit_cast(unsigned short, (__bf16)f);
}
static __device__ __forceinline__ bf16x8 bc8(s16x8 v) {
  return __builtin_bit_cast(bf16x8, v);
}
static __device__ __forceinline__ f32x16 mfma32(bf16x8 a, bf16x8 b, f32x16 c) {
  return __builtin_amdgcn_mfma_f32_32x32x16_bf16(a, b, c, 0, 0, 0);
}
static __device__ __forceinline__ f32x4 mfma16(bf16x8 a, bf16x8 b, f32x4 c) {
  return __builtin_amdgcn_mfma_f32_16x16x32_bf16(a, b, c, 0, 0, 0);
}

// async global->LDS, 16B per lane.
static __device__ __forceinline__ void gl2lds16(const unsigned short* g, unsigned short* l) {
  __builtin_amdgcn_global_load_lds(
      (const __attribute__((address_space(1))) unsigned int*)g,
      (__attribute__((address_space(3))) unsigned int*)l, 16, 0, 0);
}

// counted-vmcnt sync: wait until <= N vector-mem instrs outstanding, then barrier.
#define GSYNC(NSTR)                                          \
  do {                                                       \
    __builtin_amdgcn_sched_barrier(0);                       \
    asm volatile("s_waitcnt vmcnt(" NSTR ")" ::: "memory");  \
    __builtin_amdgcn_s_barrier();                            \
    __builtin_amdgcn_sched_barrier(0);                       \
  } while (0)

// ---------------- fused prep: cast x (blocks 0..2047) + transpose W (2048..3071) ----
__global__ void prep_k(const float* __restrict__ x, unsigned short* __restrict__ xb,
                       const float* __restrict__ W0, const float* __restrict__ W1,
                       const float* __restrict__ W2, const float* __restrict__ W3,
                       unsigned short* __restrict__ wtb) {
  __shared__ unsigned short tl[64][72];
  const int bid = blockIdx.x;
  const int t = threadIdx.x;
  if (bid < 2048) {
    int i = (bid * 256 + t) * 8;
    float4 a = *(const float4*)(x + i);
    float4 b = *(const float4*)(x + i + 4);
    s16x8 o;
    o[0] = (short)f2bf(a.x); o[1] = (short)f2bf(a.y);
    o[2] = (short)f2bf(a.z); o[3] = (short)f2bf(a.w);
    o[4] = (short)f2bf(b.x); o[5] = (short)f2bf(b.y);
    o[6] = (short)f2bf(b.z); o[7] = (short)f2bf(b.w);
    *(s16x8*)(xb + i) = o;
    return;
  }
  const int rid = bid - 2048;
  const int z = rid >> 8, rem = rid & 255;
  const float* W = z == 0 ? W0 : z == 1 ? W1 : z == 2 ? W2 : W3;
  unsigned short* out = wtb + (size_t)z * 1048576;
  const int nt = (rem & 15) * 64, kt = (rem >> 4) * 64;
  const int row = t >> 2, seg = t & 3;
  const float* src = W + (kt + row) * 1024 + nt + seg * 16;
#pragma unroll
  for (int q = 0; q < 4; ++q) {
    float4 v = *(const float4*)(src + q * 4);
    tl[seg * 16 + q * 4 + 0][row] = f2bf(v.x);
    tl[seg * 16 + q * 4 + 1][row] = f2bf(v.y);
    tl[seg * 16 + q * 4 + 2][row] = f2bf(v.z);
    tl[seg * 16 + q * 4 + 3][row] = f2bf(v.w);
  }
  __syncthreads();
  unsigned short* dst = out + (nt + row) * 1024 + kt + seg * 16;
  *(s16x8*)dst       = *(const s16x8*)&tl[row][seg * 16];
  *(s16x8*)(dst + 8) = *(const s16x8*)&tl[row][seg * 16 + 8];
}

static __device__ __forceinline__ int trans_ix(int m, int n) {
  int b = m >> 11, tt = m & 2047, h = n >> 6, dh = n & 63;
  return ((b << 4) + h) * 131072 + tt * 64 + dh;
}

// ======== fused QKV GEMM (r13): 128x192 tile, BK=64, 2 blocks/CU; V TRANSPOSED ====
__global__ __launch_bounds__(512, 4) void gemm_qkv_k(const unsigned short* __restrict__ A,
                                                     const unsigned short* __restrict__ BT,
                                                     const float* __restrict__ b0,
                                                     const float* __restrict__ b1,
                                                     const float* __restrict__ b2,
                                                     float* __restrict__ outF,
                                                     unsigned short* __restrict__ oq,
                                                     unsigned short* __restrict__ ok,
                                                     unsigned short* __restrict__ ovT) {
  extern __shared__ unsigned short lds[];
  const int t = threadIdx.x;
  const int lane = t & 63, ln = lane & 15, g = lane >> 4;
  const int w = t >> 6, wm = w >> 2, wn = w & 3;  // 2 (M) x 4 (N)
  const unsigned wgid = blockIdx.x;
  const unsigned swz = (wgid & 7) * 64 + (wgid >> 3);  // XCD-contiguous (512%8==0)
  const int by = swz & 31, bx = swz >> 5;              // by fast -> 2 B-panels/XCD
  const int bm0 = by * 128, bn0 = bx * 192;

  const int ar = t >> 2;
  const unsigned short* aBase = A + (size_t)(bm0 + ar) * 1024 + (((t & 3) ^ ((ar >> 1) & 3)) * 8);
  const int br = t >> 3;
  const int bcol = (t & 7) ^ (br & 7);
  const unsigned short* bBase = BT + (size_t)(bn0 + br) * 1024 + bcol * 8;

  auto issueA = [&](int buf, int H, int kt) {
    gl2lds16(aBase + kt + H * 32, &lds[buf * 20480 + H * 4096 + t * 8]);
  };
  auto issueB = [&](int buf, int j, int kt) {
    gl2lds16(bBase + (size_t)j * 65536 + kt, &lds[buf * 20480 + 8192 + j * 4096 + t * 8]);
  };
  auto ldA = [&](int buf, int H, int mf) -> bf16x8 {
    const int row = wm * 64 + mf * 16 + ln;
    const int sp = g ^ ((row >> 1) & 3);
    return bc8(*(const s16x8*)&lds[buf * 20480 + H * 4096 + row * 32 + sp * 8]);
  };
  auto ldB = [&](int buf, int H, int nf) -> bf16x8 {
    const int row = wn * 48 + nf * 16 + ln;
    const int sp = (H * 4 + g) ^ (row & 7);
    return bc8(*(const s16x8*)&lds[buf * 20480 + 8192 + row * 64 + sp * 8]);
  };

  f32x4 acc[4][3] = {};
  issueA(0, 0, 0);
  issueB(0, 0, 0);
  issueB(0, 1, 0);
  issueB(0, 2, 0);
  issueA(0, 1, 0);

  for (int ti = 0; ti < 16; ++ti) {
    const int buf = ti & 1, nb = buf ^ 1;
    const bool hn = ti < 15;
    const int kn = (ti + 1) * 64;

    GSYNC("1");
    if (hn) { issueA(nb, 0, kn); issueB(nb, 0, kn); issueB(nb, 1, kn); }
    {
      bf16x8 afr[4], bfr[3];
#pragma unroll
      for (int mf = 0; mf < 4; ++mf) afr[mf] = ldA(buf, 0, mf);
#pragma unroll
      for (int nf = 0; nf < 3; ++nf) bfr[nf] = ldB(buf, 0, nf);
      __builtin_amdgcn_s_setprio(1);
#pragma unroll
      for (int mf = 0; mf < 4; ++mf)
#pragma unroll
        for (int nf = 0; nf < 3; ++nf) acc[mf][nf] = mfma16(afr[mf], bfr[nf], acc[mf][nf]);
      __builtin_amdgcn_s_setprio(0);
    }
    if (hn) GSYNC("3"); else GSYNC("0");
    if (hn) { issueB(nb, 2, kn); issueA(nb, 1, kn); }
    {
      bf16x8 afr[4], bfr[3];
#pragma unroll
      for (int mf = 0; mf < 4; ++mf) afr[mf] = ldA(buf, 1, mf);
#pragma unroll
      for (int nf = 0; nf < 3; ++nf) bfr[nf] = ldB(buf, 1, nf);
      __builtin_amdgcn_s_setprio(1);
#pragma unroll
      for (int mf = 0; mf < 4; ++mf)
#pragma unroll
        for (int nf = 0; nf < 3; ++nf) acc[mf][nf] = mfma16(afr[mf], bfr[nf], acc[mf][nf]);
      __builtin_amdgcn_s_setprio(0);
    }
  }

#pragma unroll
  for (int nf = 0; nf < 3; ++nf) {
    const int n = bn0 + wn * 48 + nf * 16 + ln;
    const int n1 = n & 1023;
    const float* bp = n < 1024 ? b0 : (n < 2048 ? b1 : b2);
    const float bias = bp[n1];
    if (n < 1024) {
#pragma unroll
      for (int mf = 0; mf < 4; ++mf)
#pragma unroll
        for (int r = 0; r < 4; ++r) {
          const int m = bm0 + wm * 64 + mf * 16 + g * 4 + r;
          oq[trans_ix(m, n1)] = f2bf((acc[mf][nf][r] + bias) * 0.18033688f);  // 0.125*log2e
        }
    } else if (n < 2048) {
#pragma unroll
      for (int mf = 0; mf < 4; ++mf)
#pragma unroll
        for (int r = 0; r < 4; ++r) {
          const int m = bm0 + wm * 64 + mf * 16 + g * 4 + r;
          const float v = acc[mf][nf][r] + bias;
          const int ix = trans_ix(m, n1);
          ok[ix] = f2bf(v);
          outF[4194304 + ix] = v;
        }
    } else {  // V: fp32 normal layout + bf16 TRANSPOSED [bh][dh][t] (packed 8B)
      const int dh = n1 & 63, hh = n1 >> 6;
#pragma unroll
      for (int mf = 0; mf < 4; ++mf) {
        const int m0 = bm0 + wm * 64 + mf * 16 + g * 4;
        const int bb = m0 >> 11, tt = m0 & 2047;
        s16x4 pv;
#pragma unroll
        for (int r = 0; r < 4; ++r) {
          const float v = acc[mf][nf][r] + bias;
          outF[8388608 + trans_ix(m0 + r, n1)] = v;
          pv[r] = (short)f2bf(v);
        }
        *(s16x4*)(ovT + (size_t)((bb << 4) + hh) * 131072 + (size_t)dh * 2048 + tt) = pv;
      }
    }
  }
}

// ======== O-proj GEMM (r13): BM=64, BN=128, BK=64, counted vmcnt ========
__global__ __launch_bounds__(512, 4) void gemm_o_k(const unsigned short* __restrict__ A,
                                                   const unsigned short* __restrict__ BT,
                                                   const float* __restrict__ b0,
                                                   float* __restrict__ outF) {
  extern __shared__ unsigned short lds[];
  const int t = threadIdx.x;
  const int lane = t & 63, ln = lane & 15, g = lane >> 4;
  const int w = t >> 6, wm = w >> 2, wn = w & 3;
  const unsigned wgid = blockIdx.x;
  const unsigned swz = (wgid & 7) * 64 + (wgid >> 3);
  const int bx = swz & 7, by = swz >> 3;
  const int bm0 = by * 64, bn0 = bx * 128;

  const int row = t >> 3;
  const int scol = (t & 7) ^ (row & 7);
  const unsigned short* aSrc = A + (size_t)(bm0 + row) * 1024 + scol * 8;
  const unsigned short* bSrc0 = BT + (size_t)(bn0 + row) * 1024 + scol * 8;
  const unsigned short* bSrc1 = BT + (size_t)(bn0 + 64 + row) * 1024 + scol * 8;

  auto issue3 = [&](int buf, int ti) {
    const int kt = ti * 64;
    gl2lds16(aSrc + kt, &lds[buf * 12288 + t * 8]);
    gl2lds16(bSrc0 + kt, &lds[buf * 12288 + 4096 + t * 8]);
    gl2lds16(bSrc1 + kt, &lds[buf * 12288 + 8192 + t * 8]);
  };
  auto ldA = [&](int buf, int H, int mf) -> bf16x8 {
    const int r = wm * 32 + mf * 16 + ln;
    const int sp = (H * 4 + g) ^ (r & 7);
    return bc8(*(const s16x8*)&lds[buf * 12288 + r * 64 + sp * 8]);
  };
  auto ldB = [&](int buf, int H, int nf) -> bf16x8 {
    const int r = wn * 32 + nf * 16 + ln;
    const int j = r >> 6, rl = r & 63;
    const int sp = (H * 4 + g) ^ (rl & 7);
    return bc8(*(const s16x8*)&lds[buf * 12288 + 4096 + j * 4096 + rl * 64 + sp * 8]);
  };

  f32x4 acc[2][2] = {};
  issue3(0, 0);
  issue3(1, 1);

  for (int i = 0; i < 16; ++i) {
    const int buf = i & 1;
    if (i < 15) GSYNC("3"); else GSYNC("0");
    bf16x8 a0[2], a1[2], bq0[2], bq1[2];
#pragma unroll
    for (int mf = 0; mf < 2; ++mf) { a0[mf] = ldA(buf, 0, mf); a1[mf] = ldA(buf, 1, mf); }
#pragma unroll
    for (int nf = 0; nf < 2; ++nf) { bq0[nf] = ldB(buf, 0, nf); bq1[nf] = ldB(buf, 1, nf); }
    asm volatile("s_waitcnt lgkmcnt(0)" ::: "memory");
    __builtin_amdgcn_sched_barrier(0);
    __builtin_amdgcn_s_barrier();
    __builtin_amdgcn_sched_barrier(0);
    if (i + 2 < 16) issue3(buf, i + 2);
    __builtin_amdgcn_s_setprio(1);
#pragma unroll
    for (int mf = 0; mf < 2; ++mf)
#pragma unroll
      for (int nf = 0; nf < 2; ++nf) {
        acc[mf][nf] = mfma16(a0[mf], bq0[nf], acc[mf][nf]);
        acc[mf][nf] = mfma16(a1[mf], bq1[nf], acc[mf][nf]);
      }
    __builtin_amdgcn_s_setprio(0);
  }

#pragma unroll
  for (int nf = 0; nf < 2; ++nf) {
    const int n = bn0 + wn * 32 + nf * 16 + ln;
    const float bias = b0[n];
#pragma unroll
    for (int mf = 0; mf < 2; ++mf)
#pragma unroll
      for (int r = 0; r < 4; ++r) {
        const int m = bm0 + wm * 32 + mf * 16 + g * 4 + r;
        outF[(size_t)m * 1024 + n] = acc[mf][nf][r] + bias;
      }
  }
}

// ---------------- flash attention v10 (r13): 12 waves, 3 contiguous kv-groups ----
__global__ __launch_bounds__(768) void attn_k(const unsigned short* __restrict__ qb,
                                              const unsigned short* __restrict__ kb,
                                              const unsigned short* __restrict__ vbT,
                                              unsigned short* __restrict__ ob) {
  extern __shared__ s16x8 kvS[];  // 3 grp x 3 buf x (K 512 | V 512) = 9216 vec = 144KB
  const int t = threadIdx.x;
  const int lane = t & 63, l31 = lane & 31, h5 = lane >> 5;
  const int w = t >> 6, grp = w >> 2, qw = w & 3;  // w 0..11
  const unsigned wg = blockIdx.x;
  const int x = wg & 7, r_ = wg >> 3;
  const int bh = x + 8 * (r_ >> 3);
  const int p = r_ & 7;
  const int b = bh >> 4, h = bh & 15;
  const unsigned short* Qp = qb + (size_t)bh * 131072;
  const unsigned short* Kp = kb + (size_t)bh * 131072;
  const unsigned short* Vp = vbT + (size_t)bh * 131072;

  const int e0 = t & 255;
  const int kr0 = e0 >> 3;
  const int kcol = (e0 & 7) ^ (kr0 & 7);
  const unsigned short* kSrc = Kp + (size_t)kr0 * 64 + kcol * 8;
  const unsigned short* vSrc = Vp + (size_t)kr0 * 2048 + kcol * 8;
  s16x8* gB = &kvS[grp * 3072];

  s16x8 onesv;
#pragma unroll
  for (int z = 0; z < 8; ++z) onesv[z] = (short)0x3F80;  // bf16 1.0
  const bf16x8 onesf = bc8(onesv);

  float* sc = (float*)kvS;
  const int slot = qw * 64 + lane;

  for (int half = 0; half < 2; ++half) {
    const int qblk = half == 0 ? p : 15 - p;
    const int q0 = qblk * 128;
    const int N64 = 2 * qblk + 2;
    const int base = N64 / 3, rem3 = N64 % 3;
    const int cnt = base + (grp < rem3 ? 1 : 0);
    const int start = grp * base + (grp < rem3 ? grp : rem3);
    const int NP = base + (rem3 ? 1 : 0);
    const int qg = q0 + qw * 32 + l31;

    __syncthreads();

    bf16x8 qf[4];
#pragma unroll
    for (int m = 0; m < 4; ++m)
      qf[m] = bc8(*(const s16x8*)(Qp + (size_t)qg * 64 + 16 * m + 8 * h5));

    auto issue = [&](int T, int buf) {
      const int kv0 = T * 64;
      unsigned short* kd = (unsigned short*)&gB[buf * 1024];
      unsigned short* vd = (unsigned short*)&gB[buf * 1024 + 512];
      const unsigned short* ks = kSrc + (size_t)kv0 * 64;
      const unsigned short* vs = vSrc + kv0;
      gl2lds16(ks,         kd + e0 * 8);
      gl2lds16(ks + 2048,  kd + (e0 + 256) * 8);
      gl2lds16(vs,         vd + e0 * 8);
      gl2lds16(vs + 65536, vd + (e0 + 256) * 8);
    };

    if (cnt > 0) issue(start, 0);
    if (cnt > 1) issue(start + 1, 1);

    f32x16 o0 = {}, o1 = {}, lsum = {};

    for (int i = 0; i < NP; ++i) {
      __builtin_amdgcn_sched_barrier(0);
      if (i + 1 < cnt) asm volatile("s_waitcnt vmcnt(4)" ::: "memory");
      else             asm volatile("s_waitcnt vmcnt(0)" ::: "memory");
      __builtin_amdgcn_s_barrier();
      __builtin_amdgcn_sched_barrier(0);
      if (i + 2 < cnt) issue(start + i + 2, (i + 2) % 3);
      const int T = start + i;
      const int kv0 = T * 64;
      const bool active = (i < cnt) && (kv0 <= q0 + qw * 32 + 31);
      if (active) {
        const int buf = i % 3;
        const s16x8* kb_ = &gB[buf * 1024];
        const s16x8* vb2 = &gB[buf * 1024 + 512];
        f32x16 s0 = {}, s1 = {};
        __builtin_amdgcn_s_setprio(1);
#pragma unroll
        for (int m = 0; m < 4; ++m) {
          const int sl = 2 * m + h5;
          bf16x8 a0 = bc8(kb_[l31 * 8 + (sl ^ (l31 & 7))]);
          bf16x8 a1 = bc8(kb_[(l31 + 32) * 8 + (sl ^ (l31 & 7))]);
          s0 = mfma32(a0, qf[m], s0);
          s1 = mfma32(a1, qf[m], s1);
        }
        __builtin_amdgcn_s_setprio(0);
        if (kv0 + 63 > q0 + qw * 32) {
#pragma unroll
          for (int r = 0; r < 16; ++r) {
            const int kvr = kv0 + (r & 3) + 8 * (r >> 2) + 4 * h5;
            if (kvr > qg) s0[r] = -1e30f;
            if (kvr + 32 > qg) s1[r] = -1e30f;
          }
        }
#pragma unroll
        for (int r = 0; r < 16; ++r) {
          s0[r] = __builtin_amdgcn_exp2f(s0[r]);
          s1[r] = __builtin_amdgcn_exp2f(s1[r]);
        }
        unsigned og[2][4][2];
#pragma unroll
        for (int gg = 0; gg < 4; ++gg) {
          asm("v_cvt_pk_bf16_f32 %0, %1, %2" : "=v"(og[0][gg][0]) : "v"(s0[4 * gg]),     "v"(s0[4 * gg + 1]));
          asm("v_cvt_pk_bf16_f32 %0, %1, %2" : "=v"(og[0][gg][1]) : "v"(s0[4 * gg + 2]), "v"(s0[4 * gg + 3]));
          asm("v_cvt_pk_bf16_f32 %0, %1, %2" : "=v"(og[1][gg][0]) : "v"(s1[4 * gg]),     "v"(s1[4 * gg + 1]));
          asm("v_cvt_pk_bf16_f32 %0, %1, %2" : "=v"(og[1][gg][1]) : "v"(s1[4 * gg + 2]), "v"(s1[4 * gg + 3]));
        }
        bf16x8 pf[4];
#pragma unroll
        for (int mp = 0; mp < 4; ++mp) {
          const int tau = mp >> 1, lc = mp & 1;
          unsigned a0 = og[tau][2 * lc][0], bq0 = og[tau][2 * lc + 1][0];
          unsigned a1 = og[tau][2 * lc][1], bq1 = og[tau][2 * lc + 1][1];
          asm volatile("v_permlane32_swap_b32 %0, %1" : "+v"(a0), "+v"(bq0));
          asm volatile("v_permlane32_swap_b32 %0, %1" : "+v"(a1), "+v"(bq1));
          u32x4 fw; fw[0] = a0; fw[1] = a1; fw[2] = bq0; fw[3] = bq1;
          pf[mp] = __builtin_bit_cast(bf16x8, fw);
        }
        __builtin_amdgcn_s_setprio(1);
#pragma unroll
        for (int mp = 0; mp < 4; ++mp) {
          const int sl = 2 * mp + h5;
          bf16x8 va0 = bc8(vb2[l31 * 8 + (sl ^ (l31 & 7))]);
          bf16x8 va1 = bc8(vb2[(l31 + 32) * 8 + (sl ^ (l31 & 7))]);
          o0 = mfma32(va0, pf[mp], o0);
          o1 = mfma32(va1, pf[mp], o1);
          lsum = mfma32(onesf, pf[mp], lsum);
        }
        __builtin_amdgcn_s_setprio(0);
      }
    }

    __syncthreads();
    if (grp > 0) {
      float* dst = sc + (size_t)(grp - 1) * 8704 + (size_t)slot * 34;
#pragma unroll
      for (int r = 0; r < 8; ++r) {
        *(float2*)(dst + 2 * r)      = make_float2(o0[2 * r], o0[2 * r + 1]);
        *(float2*)(dst + 16 + 2 * r) = make_float2(o1[2 * r], o1[2 * r + 1]);
      }
      dst[32] = lsum[0];
    }
    __syncthreads();
    if (grp == 0) {
      const float* p0 = sc + (size_t)slot * 34;
      const float* p1 = p0 + 8704;
      const float inv = 1.0f / (lsum[0] + p0[32] + p1[32]);
      unsigned short* orow = ob + (size_t)(b * 2048 + qg) * 1024 + h * 64;
#pragma unroll
      for (int rq = 0; rq < 4; ++rq) {
        s16x4 ov0, ov1;
#pragma unroll
        for (int e = 0; e < 4; ++e) {
          const int ei = 4 * rq + e;
          ov0[e] = (short)f2bf((o0[ei] + p0[ei] + p1[ei]) * inv);
          ov1[e] = (short)f2bf((o1[ei] + p0[16 + ei] + p1[16 + ei]) * inv);
        }
        *(s16x4*)(orow + 8 * rq + 4 * h5)      = ov0;
        *(s16x4*)(orow + 32 + 8 * rq + 4 * h5) = ov1;
      }
    }
  }
}

extern "C" void kernel_launch(void* const* d_in, const int* in_sizes, int n_in,
                              void* d_out, int out_size, void* d_ws, size_t ws_size,
                              hipStream_t stream) {
  (void)in_sizes; (void)n_in; (void)out_size; (void)ws_size;
  const float* x  = (const float*)d_in[0];
  const float* Wq = (const float*)d_in[1];
  const float* bq = (const float*)d_in[2];
  const float* Wk = (const float*)d_in[3];
  const float* bk = (const float*)d_in[4];
  const float* Wv = (const float*)d_in[5];
  const float* bv = (const float*)d_in[6];
  const float* Wo = (const float*)d_in[7];
  const float* bo = (const float*)d_in[8];
  float* out = (float*)d_out;

  unsigned short* ws  = (unsigned short*)d_ws;
  unsigned short* xb  = ws;
  unsigned short* wtb = ws + 4194304;
  unsigned short* qbuf = ws + 8388608;
  unsigned short* kbuf = qbuf + 4194304;
  unsigned short* vbuf = kbuf + 4194304;   // holds V TRANSPOSED [bh][dh][t]
  unsigned short* ab   = vbuf + 4194304;

  prep_k<<<3072, 256, 0, stream>>>(x, xb, Wq, Wk, Wv, Wo, wtb);
  gemm_qkv_k<<<512, 512, 81920, stream>>>(xb, wtb, bq, bk, bv, out, qbuf, kbuf, vbuf);
  attn_k<<<256, 768, 147456, stream>>>(qbuf, kbuf, vbuf, ab);
  gemm_o_k<<<512, 512, 49152, stream>>>(ab, wtb + 3145728, bo, out);
}

// Round 19
// 92.766 us; speedup vs baseline: 1.0584x; 1.0119x over previous
//
#include <hip/hip_runtime.h>

typedef float  f32x4  __attribute__((ext_vector_type(4)));
typedef float  f32x16 __attribute__((ext_vector_type(16)));
typedef __bf16 bf16x8 __attribute__((ext_vector_type(8)));
typedef short  s16x8  __attribute__((ext_vector_type(8)));
typedef short  s16x4  __attribute__((ext_vector_type(4)));
typedef unsigned int u32x4 __attribute__((ext_vector_type(4)));

static __device__ __forceinline__ unsigned short f2bf(float f) {
  return __builtin_bit_cast(unsigned short, (__bf16)f);
}
static __device__ __forceinline__ bf16x8 bc8(s16x8 v) {
  return __builtin_bit_cast(bf16x8, v);
}
static __device__ __forceinline__ f32x16 mfma32(bf16x8 a, bf16x8 b, f32x16 c) {
  return __builtin_amdgcn_mfma_f32_32x32x16_bf16(a, b, c, 0, 0, 0);
}
static __device__ __forceinline__ f32x4 mfma16(bf16x8 a, bf16x8 b, f32x4 c) {
  return __builtin_amdgcn_mfma_f32_16x16x32_bf16(a, b, c, 0, 0, 0);
}

// async global->LDS, 16B per lane.
static __device__ __forceinline__ void gl2lds16(const unsigned short* g, unsigned short* l) {
  __builtin_amdgcn_global_load_lds(
      (const __attribute__((address_space(1))) unsigned int*)g,
      (__attribute__((address_space(3))) unsigned int*)l, 16, 0, 0);
}

// counted-vmcnt sync: wait until <= N vector-mem instrs outstanding, then barrier.
#define GSYNC(NSTR)                                          \
  do {                                                       \
    __builtin_amdgcn_sched_barrier(0);                       \
    asm volatile("s_waitcnt vmcnt(" NSTR ")" ::: "memory");  \
    __builtin_amdgcn_s_barrier();                            \
    __builtin_amdgcn_sched_barrier(0);                       \
  } while (0)

// ---------------- fused prep: cast x (blocks 0..2047) + transpose W (2048..3071) ----
__global__ void prep_k(const float* __restrict__ x, unsigned short* __restrict__ xb,
                       const float* __restrict__ W0, const float* __restrict__ W1,
                       const float* __restrict__ W2, const float* __restrict__ W3,
                       unsigned short* __restrict__ wtb) {
  __shared__ unsigned short tl[64][72];
  const int bid = blockIdx.x;
  const int t = threadIdx.x;
  if (bid < 2048) {
    int i = (bid * 256 + t) * 8;
    float4 a = *(const float4*)(x + i);
    float4 b = *(const float4*)(x + i + 4);
    s16x8 o;
    o[0] = (short)f2bf(a.x); o[1] = (short)f2bf(a.y);
    o[2] = (short)f2bf(a.z); o[3] = (short)f2bf(a.w);
    o[4] = (short)f2bf(b.x); o[5] = (short)f2bf(b.y);
    o[6] = (short)f2bf(b.z); o[7] = (short)f2bf(b.w);
    *(s16x8*)(xb + i) = o;
    return;
  }
  const int rid = bid - 2048;
  const int z = rid >> 8, rem = rid & 255;
  const float* W = z == 0 ? W0 : z == 1 ? W1 : z == 2 ? W2 : W3;
  unsigned short* out = wtb + (size_t)z * 1048576;
  const int nt = (rem & 15) * 64, kt = (rem >> 4) * 64;
  const int row = t >> 2, seg = t & 3;
  const float* src = W + (kt + row) * 1024 + nt + seg * 16;
#pragma unroll
  for (int q = 0; q < 4; ++q) {
    float4 v = *(const float4*)(src + q * 4);
    tl[seg * 16 + q * 4 + 0][row] = f2bf(v.x);
    tl[seg * 16 + q * 4 + 1][row] = f2bf(v.y);
    tl[seg * 16 + q * 4 + 2][row] = f2bf(v.z);
    tl[seg * 16 + q * 4 + 3][row] = f2bf(v.w);
  }
  __syncthreads();
  unsigned short* dst = out + (nt + row) * 1024 + kt + seg * 16;
  *(s16x8*)dst       = *(const s16x8*)&tl[row][seg * 16];
  *(s16x8*)(dst + 8) = *(const s16x8*)&tl[row][seg * 16 + 8];
}

static __device__ __forceinline__ int trans_ix(int m, int n) {
  int b = m >> 11, tt = m & 2047, h = n >> 6, dh = n & 63;
  return ((b << 4) + h) * 131072 + tt * 64 + dh;
}

// ======== fused QKV GEMM (r13 + 2D XCD chunking): 128x192 tile, BK=64, 2 blk/CU ====
// XCD c owns an 8(by) x 8(bx) chunk: byc = c&3, bxc = c>>2 -> per-XCD working set
// A 2MB + B 3MB ~= L2 (was: all 32 A-panels = 8MB -> constant refetch).
__global__ __launch_bounds__(512, 4) void gemm_qkv_k(const unsigned short* __restrict__ A,
                                                     const unsigned short* __restrict__ BT,
                                                     const float* __restrict__ b0,
                                                     const float* __restrict__ b1,
                                                     const float* __restrict__ b2,
                                                     float* __restrict__ outF,
                                                     unsigned short* __restrict__ oq,
                                                     unsigned short* __restrict__ ok,
                                                     unsigned short* __restrict__ ovT) {
  extern __shared__ unsigned short lds[];
  const int t = threadIdx.x;
  const int lane = t & 63, ln = lane & 15, g = lane >> 4;
  const int w = t >> 6, wm = w >> 2, wn = w & 3;  // 2 (M) x 4 (N)
  const unsigned wgid = blockIdx.x;
  const int xcd = wgid & 7;
  const int loc = wgid >> 3;            // 0..63 within XCD
  const int by = (xcd & 3) * 8 + (loc & 7);
  const int bx = (xcd >> 2) * 8 + (loc >> 3);
  const int bm0 = by * 128, bn0 = bx * 192;

  const int ar = t >> 2;
  const unsigned short* aBase = A + (size_t)(bm0 + ar) * 1024 + (((t & 3) ^ ((ar >> 1) & 3)) * 8);
  const int br = t >> 3;
  const int bcol = (t & 7) ^ (br & 7);
  const unsigned short* bBase = BT + (size_t)(bn0 + br) * 1024 + bcol * 8;

  auto issueA = [&](int buf, int H, int kt) {
    gl2lds16(aBase + kt + H * 32, &lds[buf * 20480 + H * 4096 + t * 8]);
  };
  auto issueB = [&](int buf, int j, int kt) {
    gl2lds16(bBase + (size_t)j * 65536 + kt, &lds[buf * 20480 + 8192 + j * 4096 + t * 8]);
  };
  auto ldA = [&](int buf, int H, int mf) -> bf16x8 {
    const int row = wm * 64 + mf * 16 + ln;
    const int sp = g ^ ((row >> 1) & 3);
    return bc8(*(const s16x8*)&lds[buf * 20480 + H * 4096 + row * 32 + sp * 8]);
  };
  auto ldB = [&](int buf, int H, int nf) -> bf16x8 {
    const int row = wn * 48 + nf * 16 + ln;
    const int sp = (H * 4 + g) ^ (row & 7);
    return bc8(*(const s16x8*)&lds[buf * 20480 + 8192 + row * 64 + sp * 8]);
  };

  f32x4 acc[4][3] = {};
  issueA(0, 0, 0);
  issueB(0, 0, 0);
  issueB(0, 1, 0);
  issueB(0, 2, 0);
  issueA(0, 1, 0);

  for (int ti = 0; ti < 16; ++ti) {
    const int buf = ti & 1, nb = buf ^ 1;
    const bool hn = ti < 15;
    const int kn = (ti + 1) * 64;

    GSYNC("1");
    if (hn) { issueA(nb, 0, kn); issueB(nb, 0, kn); issueB(nb, 1, kn); }
    {
      bf16x8 afr[4], bfr[3];
#pragma unroll
      for (int mf = 0; mf < 4; ++mf) afr[mf] = ldA(buf, 0, mf);
#pragma unroll
      for (int nf = 0; nf < 3; ++nf) bfr[nf] = ldB(buf, 0, nf);
      __builtin_amdgcn_s_setprio(1);
#pragma unroll
      for (int mf = 0; mf < 4; ++mf)
#pragma unroll
        for (int nf = 0; nf < 3; ++nf) acc[mf][nf] = mfma16(afr[mf], bfr[nf], acc[mf][nf]);
      __builtin_amdgcn_s_setprio(0);
    }
    if (hn) GSYNC("3"); else GSYNC("0");
    if (hn) { issueB(nb, 2, kn); issueA(nb, 1, kn); }
    {
      bf16x8 afr[4], bfr[3];
#pragma unroll
      for (int mf = 0; mf < 4; ++mf) afr[mf] = ldA(buf, 1, mf);
#pragma unroll
      for (int nf = 0; nf < 3; ++nf) bfr[nf] = ldB(buf, 1, nf);
      __builtin_amdgcn_s_setprio(1);
#pragma unroll
      for (int mf = 0; mf < 4; ++mf)
#pragma unroll
        for (int nf = 0; nf < 3; ++nf) acc[mf][nf] = mfma16(afr[mf], bfr[nf], acc[mf][nf]);
      __builtin_amdgcn_s_setprio(0);
    }
  }

#pragma unroll
  for (int nf = 0; nf < 3; ++nf) {
    const int n = bn0 + wn * 48 + nf * 16 + ln;
    const int n1 = n & 1023;
    const float* bp = n < 1024 ? b0 : (n < 2048 ? b1 : b2);
    const float bias = bp[n1];
    if (n < 1024) {
#pragma unroll
      for (int mf = 0; mf < 4; ++mf)
#pragma unroll
        for (int r = 0; r < 4; ++r) {
          const int m = bm0 + wm * 64 + mf * 16 + g * 4 + r;
          oq[trans_ix(m, n1)] = f2bf((acc[mf][nf][r] + bias) * 0.18033688f);  // 0.125*log2e
        }
    } else if (n < 2048) {
#pragma unroll
      for (int mf = 0; mf < 4; ++mf)
#pragma unroll
        for (int r = 0; r < 4; ++r) {
          const int m = bm0 + wm * 64 + mf * 16 + g * 4 + r;
          const float v = acc[mf][nf][r] + bias;
          const int ix = trans_ix(m, n1);
          ok[ix] = f2bf(v);
          outF[4194304 + ix] = v;
        }
    } else {  // V: fp32 normal layout + bf16 TRANSPOSED [bh][dh][t] (packed 8B)
      const int dh = n1 & 63, hh = n1 >> 6;
#pragma unroll
      for (int mf = 0; mf < 4; ++mf) {
        const int m0 = bm0 + wm * 64 + mf * 16 + g * 4;
        const int bb = m0 >> 11, tt = m0 & 2047;
        s16x4 pv;
#pragma unroll
        for (int r = 0; r < 4; ++r) {
          const float v = acc[mf][nf][r] + bias;
          outF[8388608 + trans_ix(m0 + r, n1)] = v;
          pv[r] = (short)f2bf(v);
        }
        *(s16x4*)(ovT + (size_t)((bb << 4) + hh) * 131072 + (size_t)dh * 2048 + tt) = pv;
      }
    }
  }
}

// ======== O-proj GEMM (r13): BM=64, BN=128, BK=64, counted vmcnt ========
__global__ __launch_bounds__(512, 4) void gemm_o_k(const unsigned short* __restrict__ A,
                                                   const unsigned short* __restrict__ BT,
                                                   const float* __restrict__ b0,
                                                   float* __restrict__ outF) {
  extern __shared__ unsigned short lds[];
  const int t = threadIdx.x;
  const int lane = t & 63, ln = lane & 15, g = lane >> 4;
  const int w = t >> 6, wm = w >> 2, wn = w & 3;
  const unsigned wgid = blockIdx.x;
  const unsigned swz = (wgid & 7) * 64 + (wgid >> 3);
  const int bx = swz & 7, by = swz >> 3;
  const int bm0 = by * 64, bn0 = bx * 128;

  const int row = t >> 3;
  const int scol = (t & 7) ^ (row & 7);
  const unsigned short* aSrc = A + (size_t)(bm0 + row) * 1024 + scol * 8;
  const unsigned short* bSrc0 = BT + (size_t)(bn0 + row) * 1024 + scol * 8;
  const unsigned short* bSrc1 = BT + (size_t)(bn0 + 64 + row) * 1024 + scol * 8;

  auto issue3 = [&](int buf, int ti) {
    const int kt = ti * 64;
    gl2lds16(aSrc + kt, &lds[buf * 12288 + t * 8]);
    gl2lds16(bSrc0 + kt, &lds[buf * 12288 + 4096 + t * 8]);
    gl2lds16(bSrc1 + kt, &lds[buf * 12288 + 8192 + t * 8]);
  };
  auto ldA = [&](int buf, int H, int mf) -> bf16x8 {
    const int r = wm * 32 + mf * 16 + ln;
    const int sp = (H * 4 + g) ^ (r & 7);
    return bc8(*(const s16x8*)&lds[buf * 12288 + r * 64 + sp * 8]);
  };
  auto ldB = [&](int buf, int H, int nf) -> bf16x8 {
    const int r = wn * 32 + nf * 16 + ln;
    const int j = r >> 6, rl = r & 63;
    const int sp = (H * 4 + g) ^ (rl & 7);
    return bc8(*(const s16x8*)&lds[buf * 12288 + 4096 + j * 4096 + rl * 64 + sp * 8]);
  };

  f32x4 acc[2][2] = {};
  issue3(0, 0);
  issue3(1, 1);

  for (int i = 0; i < 16; ++i) {
    const int buf = i & 1;
    if (i < 15) GSYNC("3"); else GSYNC("0");
    bf16x8 a0[2], a1[2], bq0[2], bq1[2];
#pragma unroll
    for (int mf = 0; mf < 2; ++mf) { a0[mf] = ldA(buf, 0, mf); a1[mf] = ldA(buf, 1, mf); }
#pragma unroll
    for (int nf = 0; nf < 2; ++nf) { bq0[nf] = ldB(buf, 0, nf); bq1[nf] = ldB(buf, 1, nf); }
    asm volatile("s_waitcnt lgkmcnt(0)" ::: "memory");
    __builtin_amdgcn_sched_barrier(0);
    __builtin_amdgcn_s_barrier();
    __builtin_amdgcn_sched_barrier(0);
    if (i + 2 < 16) issue3(buf, i + 2);
    __builtin_amdgcn_s_setprio(1);
#pragma unroll
    for (int mf = 0; mf < 2; ++mf)
#pragma unroll
      for (int nf = 0; nf < 2; ++nf) {
        acc[mf][nf] = mfma16(a0[mf], bq0[nf], acc[mf][nf]);
        acc[mf][nf] = mfma16(a1[mf], bq1[nf], acc[mf][nf]);
      }
    __builtin_amdgcn_s_setprio(0);
  }

#pragma unroll
  for (int nf = 0; nf < 2; ++nf) {
    const int n = bn0 + wn * 32 + nf * 16 + ln;
    const float bias = b0[n];
#pragma unroll
    for (int mf = 0; mf < 2; ++mf)
#pragma unroll
      for (int r = 0; r < 4; ++r) {
        const int m = bm0 + wm * 32 + mf * 16 + g * 4 + r;
        outF[(size_t)m * 1024 + n] = acc[mf][nf][r] + bias;
      }
  }
}

// ---------------- flash attention v10 (r13): 12 waves, 3 contiguous kv-groups ----
__global__ __launch_bounds__(768) void attn_k(const unsigned short* __restrict__ qb,
                                              const unsigned short* __restrict__ kb,
                                              const unsigned short* __restrict__ vbT,
                                              unsigned short* __restrict__ ob) {
  extern __shared__ s16x8 kvS[];  // 3 grp x 3 buf x (K 512 | V 512) = 9216 vec = 144KB
  const int t = threadIdx.x;
  const int lane = t & 63, l31 = lane & 31, h5 = lane >> 5;
  const int w = t >> 6, grp = w >> 2, qw = w & 3;  // w 0..11
  const unsigned wg = blockIdx.x;
  const int x = wg & 7, r_ = wg >> 3;
  const int bh = x + 8 * (r_ >> 3);
  const int p = r_ & 7;
  const int b = bh >> 4, h = bh & 15;
  const unsigned short* Qp = qb + (size_t)bh * 131072;
  const unsigned short* Kp = kb + (size_t)bh * 131072;
  const unsigned short* Vp = vbT + (size_t)bh * 131072;

  const int e0 = t & 255;
  const int kr0 = e0 >> 3;
  const int kcol = (e0 & 7) ^ (kr0 & 7);
  const unsigned short* kSrc = Kp + (size_t)kr0 * 64 + kcol * 8;
  const unsigned short* vSrc = Vp + (size_t)kr0 * 2048 + kcol * 8;
  s16x8* gB = &kvS[grp * 3072];

  s16x8 onesv;
#pragma unroll
  for (int z = 0; z < 8; ++z) onesv[z] = (short)0x3F80;  // bf16 1.0
  const bf16x8 onesf = bc8(onesv);

  float* sc = (float*)kvS;
  const int slot = qw * 64 + lane;

  for (int half = 0; half < 2; ++half) {
    const int qblk = half == 0 ? p : 15 - p;
    const int q0 = qblk * 128;
    const int N64 = 2 * qblk + 2;
    const int base = N64 / 3, rem3 = N64 % 3;
    const int cnt = base + (grp < rem3 ? 1 : 0);
    const int start = grp * base + (grp < rem3 ? grp : rem3);
    const int NP = base + (rem3 ? 1 : 0);
    const int qg = q0 + qw * 32 + l31;

    __syncthreads();

    bf16x8 qf[4];
#pragma unroll
    for (int m = 0; m < 4; ++m)
      qf[m] = bc8(*(const s16x8*)(Qp + (size_t)qg * 64 + 16 * m + 8 * h5));

    auto issue = [&](int T, int buf) {
      const int kv0 = T * 64;
      unsigned short* kd = (unsigned short*)&gB[buf * 1024];
      unsigned short* vd = (unsigned short*)&gB[buf * 1024 + 512];
      const unsigned short* ks = kSrc + (size_t)kv0 * 64;
      const unsigned short* vs = vSrc + kv0;
      gl2lds16(ks,         kd + e0 * 8);
      gl2lds16(ks + 2048,  kd + (e0 + 256) * 8);
      gl2lds16(vs,         vd + e0 * 8);
      gl2lds16(vs + 65536, vd + (e0 + 256) * 8);
    };

    if (cnt > 0) issue(start, 0);
    if (cnt > 1) issue(start + 1, 1);

    f32x16 o0 = {}, o1 = {}, lsum = {};

    for (int i = 0; i < NP; ++i) {
      __builtin_amdgcn_sched_barrier(0);
      if (i + 1 < cnt) asm volatile("s_waitcnt vmcnt(4)" ::: "memory");
      else             asm volatile("s_waitcnt vmcnt(0)" ::: "memory");
      __builtin_amdgcn_s_barrier();
      __builtin_amdgcn_sched_barrier(0);
      if (i + 2 < cnt) issue(start + i + 2, (i + 2) % 3);
      const int T = start + i;
      const int kv0 = T * 64;
      const bool active = (i < cnt) && (kv0 <= q0 + qw * 32 + 31);
      if (active) {
        const int buf = i % 3;
        const s16x8* kb_ = &gB[buf * 1024];
        const s16x8* vb2 = &gB[buf * 1024 + 512];
        f32x16 s0 = {}, s1 = {};
        __builtin_amdgcn_s_setprio(1);
#pragma unroll
        for (int m = 0; m < 4; ++m) {
          const int sl = 2 * m + h5;
          bf16x8 a0 = bc8(kb_[l31 * 8 + (sl ^ (l31 & 7))]);
          bf16x8 a1 = bc8(kb_[(l31 + 32) * 8 + (sl ^ (l31 & 7))]);
          s0 = mfma32(a0, qf[m], s0);
          s1 = mfma32(a1, qf[m], s1);
        }
        __builtin_amdgcn_s_setprio(0);
        if (kv0 + 63 > q0 + qw * 32) {
#pragma unroll
          for (int r = 0; r < 16; ++r) {
            const int kvr = kv0 + (r & 3) + 8 * (r >> 2) + 4 * h5;
            if (kvr > qg) s0[r] = -1e30f;
            if (kvr + 32 > qg) s1[r] = -1e30f;
          }
        }
#pragma unroll
        for (int r = 0; r < 16; ++r) {
          s0[r] = __builtin_amdgcn_exp2f(s0[r]);
          s1[r] = __builtin_amdgcn_exp2f(s1[r]);
        }
        unsigned og[2][4][2];
#pragma unroll
        for (int gg = 0; gg < 4; ++gg) {
          asm("v_cvt_pk_bf16_f32 %0, %1, %2" : "=v"(og[0][gg][0]) : "v"(s0[4 * gg]),     "v"(s0[4 * gg + 1]));
          asm("v_cvt_pk_bf16_f32 %0, %1, %2" : "=v"(og[0][gg][1]) : "v"(s0[4 * gg + 2]), "v"(s0[4 * gg + 3]));
          asm("v_cvt_pk_bf16_f32 %0, %1, %2" : "=v"(og[1][gg][0]) : "v"(s1[4 * gg]),     "v"(s1[4 * gg + 1]));
          asm("v_cvt_pk_bf16_f32 %0, %1, %2" : "=v"(og[1][gg][1]) : "v"(s1[4 * gg + 2]), "v"(s1[4 * gg + 3]));
        }
        bf16x8 pf[4];
#pragma unroll
        for (int mp = 0; mp < 4; ++mp) {
          const int tau = mp >> 1, lc = mp & 1;
          unsigned a0 = og[tau][2 * lc][0], bq0 = og[tau][2 * lc + 1][0];
          unsigned a1 = og[tau][2 * lc][1], bq1 = og[tau][2 * lc + 1][1];
          asm volatile("v_permlane32_swap_b32 %0, %1" : "+v"(a0), "+v"(bq0));
          asm volatile("v_permlane32_swap_b32 %0, %1" : "+v"(a1), "+v"(bq1));
          u32x4 fw; fw[0] = a0; fw[1] = a1; fw[2] = bq0; fw[3] = bq1;
          pf[mp] = __builtin_bit_cast(bf16x8, fw);
        }
        __builtin_amdgcn_s_setprio(1);
#pragma unroll
        for (int mp = 0; mp < 4; ++mp) {
          const int sl = 2 * mp + h5;
          bf16x8 va0 = bc8(vb2[l31 * 8 + (sl ^ (l31 & 7))]);
          bf16x8 va1 = bc8(vb2[(l31 + 32) * 8 + (sl ^ (l31 & 7))]);
          o0 = mfma32(va0, pf[mp], o0);
          o1 = mfma32(va1, pf[mp], o1);
          lsum = mfma32(onesf, pf[mp], lsum);
        }
        __builtin_amdgcn_s_setprio(0);
      }
    }

    __syncthreads();
    if (grp > 0) {
      float* dst = sc + (size_t)(grp - 1) * 8704 + (size_t)slot * 34;
#pragma unroll
      for (int r = 0; r < 8; ++r) {
        *(float2*)(dst + 2 * r)      = make_float2(o0[2 * r], o0[2 * r + 1]);
        *(float2*)(dst + 16 + 2 * r) = make_float2(o1[2 * r], o1[2 * r + 1]);
      }
      dst[32] = lsum[0];
    }
    __syncthreads();
    if (grp == 0) {
      const float* p0 = sc + (size_t)slot * 34;
      const float* p1 = p0 + 8704;
      const float inv = 1.0f / (lsum[0] + p0[32] + p1[32]);
      unsigned short* orow = ob + (size_t)(b * 2048 + qg) * 1024 + h * 64;
#pragma unroll
      for (int rq = 0; rq < 4; ++rq) {
        s16x4 ov0, ov1;
#pragma unroll
        for (int e = 0; e < 4; ++e) {
          const int ei = 4 * rq + e;
          ov0[e] = (short)f2bf((o0[ei] + p0[ei] + p1[ei]) * inv);
          ov1[e] = (short)f2bf((o1[ei] + p0[16 + ei] + p1[16 + ei]) * inv);
        }
        *(s16x4*)(orow + 8 * rq + 4 * h5)      = ov0;
        *(s16x4*)(orow + 32 + 8 * rq + 4 * h5) = ov1;
      }
    }
  }
}

extern "C" void kernel_launch(void* const* d_in, const int* in_sizes, int n_in,
                              void* d_out, int out_size, void* d_ws, size_t ws_size,
                              hipStream_t stream) {
  (void)in_sizes; (void)n_in; (void)out_size; (void)ws_size;
  const float* x  = (const float*)d_in[0];
  const float* Wq = (const float*)d_in[1];
  const float* bq = (const float*)d_in[2];
  const float* Wk = (const float*)d_in[3];
  const float* bk = (const float*)d_in[4];
  const float* Wv = (const float*)d_in[5];
  const float* bv = (const float*)d_in[6];
  const float* Wo = (const float*)d_in[7];
  const float* bo = (const float*)d_in[8];
  float* out = (float*)d_out;

  unsigned short* ws  = (unsigned short*)d_ws;
  unsigned short* xb  = ws;
  unsigned short* wtb = ws + 4194304;
  unsigned short* qbuf = ws + 8388608;
  unsigned short* kbuf = qbuf + 4194304;
  unsigned short* vbuf = kbuf + 4194304;   // holds V TRANSPOSED [bh][dh][t]
  unsigned short* ab   = vbuf + 4194304;

  prep_k<<<3072, 256, 0, stream>>>(x, xb, Wq, Wk, Wv, Wo, wtb);
  gemm_qkv_k<<<512, 512, 81920, stream>>>(xb, wtb, bq, bk, bv, out, qbuf, kbuf, vbuf);
  attn_k<<<256, 768, 147456, stream>>>(qbuf, kbuf, vbuf, ab);
  gemm_o_k<<<512, 512, 49152, stream>>>(ab, wtb + 3145728, bo, out);
}

// Round 20
// 91.706 us; speedup vs baseline: 1.0706x; 1.0116x over previous
//
#include <hip/hip_runtime.h>

typedef float  f32x4  __attribute__((ext_vector_type(4)));
typedef float  f32x16 __attribute__((ext_vector_type(16)));
typedef __bf16 bf16x8 __attribute__((ext_vector_type(8)));
typedef short  s16x8  __attribute__((ext_vector_type(8)));
typedef short  s16x4  __attribute__((ext_vector_type(4)));
typedef unsigned int u32x4 __attribute__((ext_vector_type(4)));

static __device__ __forceinline__ unsigned short f2bf(float f) {
  return __builtin_bit_cast(unsigned short, (__bf16)f);
}
static __device__ __forceinline__ bf16x8 bc8(s16x8 v) {
  return __builtin_bit_cast(bf16x8, v);
}
static __device__ __forceinline__ f32x16 mfma32(bf16x8 a, bf16x8 b, f32x16 c) {
  return __builtin_amdgcn_mfma_f32_32x32x16_bf16(a, b, c, 0, 0, 0);
}
static __device__ __forceinline__ f32x4 mfma16(bf16x8 a, bf16x8 b, f32x4 c) {
  return __builtin_amdgcn_mfma_f32_16x16x32_bf16(a, b, c, 0, 0, 0);
}

// async global->LDS, 16B per lane.
static __device__ __forceinline__ void gl2lds16(const unsigned short* g, unsigned short* l) {
  __builtin_amdgcn_global_load_lds(
      (const __attribute__((address_space(1))) unsigned int*)g,
      (__attribute__((address_space(3))) unsigned int*)l, 16, 0, 0);
}

// counted-vmcnt sync: wait until <= N vector-mem instrs outstanding, then barrier.
#define GSYNC(NSTR)                                          \
  do {                                                       \
    __builtin_amdgcn_sched_barrier(0);                       \
    asm volatile("s_waitcnt vmcnt(" NSTR ")" ::: "memory");  \
    __builtin_amdgcn_s_barrier();                            \
    __builtin_amdgcn_sched_barrier(0);                       \
  } while (0)

// ---------------- fused prep: cast x (blocks 0..2047) + transpose W (2048..3071) ----
__global__ void prep_k(const float* __restrict__ x, unsigned short* __restrict__ xb,
                       const float* __restrict__ W0, const float* __restrict__ W1,
                       const float* __restrict__ W2, const float* __restrict__ W3,
                       unsigned short* __restrict__ wtb) {
  __shared__ unsigned short tl[64][72];
  const int bid = blockIdx.x;
  const int t = threadIdx.x;
  if (bid < 2048) {
    int i = (bid * 256 + t) * 8;
    float4 a = *(const float4*)(x + i);
    float4 b = *(const float4*)(x + i + 4);
    s16x8 o;
    o[0] = (short)f2bf(a.x); o[1] = (short)f2bf(a.y);
    o[2] = (short)f2bf(a.z); o[3] = (short)f2bf(a.w);
    o[4] = (short)f2bf(b.x); o[5] = (short)f2bf(b.y);
    o[6] = (short)f2bf(b.z); o[7] = (short)f2bf(b.w);
    *(s16x8*)(xb + i) = o;
    return;
  }
  const int rid = bid - 2048;
  const int z = rid >> 8, rem = rid & 255;
  const float* W = z == 0 ? W0 : z == 1 ? W1 : z == 2 ? W2 : W3;
  unsigned short* out = wtb + (size_t)z * 1048576;
  const int nt = (rem & 15) * 64, kt = (rem >> 4) * 64;
  const int row = t >> 2, seg = t & 3;
  const float* src = W + (kt + row) * 1024 + nt + seg * 16;
#pragma unroll
  for (int q = 0; q < 4; ++q) {
    float4 v = *(const float4*)(src + q * 4);
    tl[seg * 16 + q * 4 + 0][row] = f2bf(v.x);
    tl[seg * 16 + q * 4 + 1][row] = f2bf(v.y);
    tl[seg * 16 + q * 4 + 2][row] = f2bf(v.z);
    tl[seg * 16 + q * 4 + 3][row] = f2bf(v.w);
  }
  __syncthreads();
  unsigned short* dst = out + (nt + row) * 1024 + kt + seg * 16;
  *(s16x8*)dst       = *(const s16x8*)&tl[row][seg * 16];
  *(s16x8*)(dst + 8) = *(const s16x8*)&tl[row][seg * 16 + 8];
}

static __device__ __forceinline__ int trans_ix(int m, int n) {
  int b = m >> 11, tt = m & 2047, h = n >> 6, dh = n & 63;
  return ((b << 4) + h) * 131072 + tt * 64 + dh;
}

// ======== fused QKV GEMM: 128x192 tile, BK=64, 2 blk/CU, 2D XCD chunk, ========
// ======== SINGLE-BOUNDARY phase: GSYNC(5) + lgkmcnt-split MFMA (16 syncs) ========
__global__ __launch_bounds__(512, 4) void gemm_qkv_k(const unsigned short* __restrict__ A,
                                                     const unsigned short* __restrict__ BT,
                                                     const float* __restrict__ b0,
                                                     const float* __restrict__ b1,
                                                     const float* __restrict__ b2,
                                                     float* __restrict__ outF,
                                                     unsigned short* __restrict__ oq,
                                                     unsigned short* __restrict__ ok,
                                                     unsigned short* __restrict__ ovT) {
  extern __shared__ unsigned short lds[];
  const int t = threadIdx.x;
  const int lane = t & 63, ln = lane & 15, g = lane >> 4;
  const int w = t >> 6, wm = w >> 2, wn = w & 3;  // 2 (M) x 4 (N)
  const unsigned wgid = blockIdx.x;
  const int xcd = wgid & 7;
  const int loc = wgid >> 3;            // 0..63 within XCD
  const int by = (xcd & 3) * 8 + (loc & 7);
  const int bx = (xcd >> 2) * 8 + (loc >> 3);
  const int bm0 = by * 128, bn0 = bx * 192;

  const int ar = t >> 2;
  const unsigned short* aBase = A + (size_t)(bm0 + ar) * 1024 + (((t & 3) ^ ((ar >> 1) & 3)) * 8);
  const int br = t >> 3;
  const int bcol = (t & 7) ^ (br & 7);
  const unsigned short* bBase = BT + (size_t)(bn0 + br) * 1024 + bcol * 8;

  auto issueTile = [&](int T, int buf) {  // 5 loads: A_h0, B0, B1, B2, A_h1
    const int kt = T * 64;
    gl2lds16(aBase + kt, &lds[buf * 20480 + t * 8]);
#pragma unroll
    for (int j = 0; j < 3; ++j)
      gl2lds16(bBase + (size_t)j * 65536 + kt, &lds[buf * 20480 + 8192 + j * 4096 + t * 8]);
    gl2lds16(aBase + kt + 32, &lds[buf * 20480 + 4096 + t * 8]);
  };
  auto ldA = [&](int buf, int H, int mf) -> bf16x8 {
    const int row = wm * 64 + mf * 16 + ln;
    const int sp = g ^ ((row >> 1) & 3);
    return bc8(*(const s16x8*)&lds[buf * 20480 + H * 4096 + row * 32 + sp * 8]);
  };
  auto ldB = [&](int buf, int H, int nf) -> bf16x8 {
    const int row = wn * 48 + nf * 16 + ln;
    const int sp = (H * 4 + g) ^ (row & 7);
    return bc8(*(const s16x8*)&lds[buf * 20480 + 8192 + row * 64 + sp * 8]);
  };

  f32x4 acc[4][3] = {};
  issueTile(0, 0);
  issueTile(1, 1);

  for (int ti = 0; ti < 16; ++ti) {
    const int buf = ti & 1;
    // boundary: tile ti's 5 loads landed; tile ti+1's 5 may remain in flight
    if (ti < 15) GSYNC("5"); else GSYNC("0");

    bf16x8 af0[4], bf0[3], af1[4], bf1[3];
#pragma unroll
    for (int mf = 0; mf < 4; ++mf) af0[mf] = ldA(buf, 0, mf);
#pragma unroll
    for (int nf = 0; nf < 3; ++nf) bf0[nf] = ldB(buf, 0, nf);
#pragma unroll
    for (int mf = 0; mf < 4; ++mf) af1[mf] = ldA(buf, 1, mf);
#pragma unroll
    for (int nf = 0; nf < 3; ++nf) bf1[nf] = ldB(buf, 1, nf);

    // half-0 frags ready (7 newest = half-1 reads may remain)
    asm volatile("s_waitcnt lgkmcnt(7)" ::: "memory");
    __builtin_amdgcn_sched_barrier(0);
    __builtin_amdgcn_s_setprio(1);
#pragma unroll
    for (int mf = 0; mf < 4; ++mf)
#pragma unroll
      for (int nf = 0; nf < 3; ++nf) acc[mf][nf] = mfma16(af0[mf], bf0[nf], acc[mf][nf]);
    __builtin_amdgcn_s_setprio(0);

    // all my reads of this buf done -> barrier -> refill buf with tile ti+2
    asm volatile("s_waitcnt lgkmcnt(0)" ::: "memory");
    __builtin_amdgcn_sched_barrier(0);
    __builtin_amdgcn_s_barrier();
    __builtin_amdgcn_sched_barrier(0);
    if (ti + 2 < 16) issueTile(ti + 2, buf);

    __builtin_amdgcn_s_setprio(1);
#pragma unroll
    for (int mf = 0; mf < 4; ++mf)
#pragma unroll
      for (int nf = 0; nf < 3; ++nf) acc[mf][nf] = mfma16(af1[mf], bf1[nf], acc[mf][nf]);
    __builtin_amdgcn_s_setprio(0);
  }

#pragma unroll
  for (int nf = 0; nf < 3; ++nf) {
    const int n = bn0 + wn * 48 + nf * 16 + ln;
    const int n1 = n & 1023;
    const float* bp = n < 1024 ? b0 : (n < 2048 ? b1 : b2);
    const float bias = bp[n1];
    if (n < 1024) {
#pragma unroll
      for (int mf = 0; mf < 4; ++mf)
#pragma unroll
        for (int r = 0; r < 4; ++r) {
          const int m = bm0 + wm * 64 + mf * 16 + g * 4 + r;
          oq[trans_ix(m, n1)] = f2bf((acc[mf][nf][r] + bias) * 0.18033688f);  // 0.125*log2e
        }
    } else if (n < 2048) {
#pragma unroll
      for (int mf = 0; mf < 4; ++mf)
#pragma unroll
        for (int r = 0; r < 4; ++r) {
          const int m = bm0 + wm * 64 + mf * 16 + g * 4 + r;
          const float v = acc[mf][nf][r] + bias;
          const int ix = trans_ix(m, n1);
          ok[ix] = f2bf(v);
          outF[4194304 + ix] = v;
        }
    } else {  // V: fp32 normal layout + bf16 TRANSPOSED [bh][dh][t] (packed 8B)
      const int dh = n1 & 63, hh = n1 >> 6;
#pragma unroll
      for (int mf = 0; mf < 4; ++mf) {
        const int m0 = bm0 + wm * 64 + mf * 16 + g * 4;
        const int bb = m0 >> 11, tt = m0 & 2047;
        s16x4 pv;
#pragma unroll
        for (int r = 0; r < 4; ++r) {
          const float v = acc[mf][nf][r] + bias;
          outF[8388608 + trans_ix(m0 + r, n1)] = v;
          pv[r] = (short)f2bf(v);
        }
        *(s16x4*)(ovT + (size_t)((bb << 4) + hh) * 131072 + (size_t)dh * 2048 + tt) = pv;
      }
    }
  }
}

// ======== O-proj GEMM (r13): BM=64, BN=128, BK=64, counted vmcnt ========
__global__ __launch_bounds__(512, 4) void gemm_o_k(const unsigned short* __restrict__ A,
                                                   const unsigned short* __restrict__ BT,
                                                   const float* __restrict__ b0,
                                                   float* __restrict__ outF) {
  extern __shared__ unsigned short lds[];
  const int t = threadIdx.x;
  const int lane = t & 63, ln = lane & 15, g = lane >> 4;
  const int w = t >> 6, wm = w >> 2, wn = w & 3;
  const unsigned wgid = blockIdx.x;
  const unsigned swz = (wgid & 7) * 64 + (wgid >> 3);
  const int bx = swz & 7, by = swz >> 3;
  const int bm0 = by * 64, bn0 = bx * 128;

  const int row = t >> 3;
  const int scol = (t & 7) ^ (row & 7);
  const unsigned short* aSrc = A + (size_t)(bm0 + row) * 1024 + scol * 8;
  const unsigned short* bSrc0 = BT + (size_t)(bn0 + row) * 1024 + scol * 8;
  const unsigned short* bSrc1 = BT + (size_t)(bn0 + 64 + row) * 1024 + scol * 8;

  auto issue3 = [&](int buf, int ti) {
    const int kt = ti * 64;
    gl2lds16(aSrc + kt, &lds[buf * 12288 + t * 8]);
    gl2lds16(bSrc0 + kt, &lds[buf * 12288 + 4096 + t * 8]);
    gl2lds16(bSrc1 + kt, &lds[buf * 12288 + 8192 + t * 8]);
  };
  auto ldA = [&](int buf, int H, int mf) -> bf16x8 {
    const int r = wm * 32 + mf * 16 + ln;
    const int sp = (H * 4 + g) ^ (r & 7);
    return bc8(*(const s16x8*)&lds[buf * 12288 + r * 64 + sp * 8]);
  };
  auto ldB = [&](int buf, int H, int nf) -> bf16x8 {
    const int r = wn * 32 + nf * 16 + ln;
    const int j = r >> 6, rl = r & 63;
    const int sp = (H * 4 + g) ^ (rl & 7);
    return bc8(*(const s16x8*)&lds[buf * 12288 + 4096 + j * 4096 + rl * 64 + sp * 8]);
  };

  f32x4 acc[2][2] = {};
  issue3(0, 0);
  issue3(1, 1);

  for (int i = 0; i < 16; ++i) {
    const int buf = i & 1;
    if (i < 15) GSYNC("3"); else GSYNC("0");
    bf16x8 a0[2], a1[2], bq0[2], bq1[2];
#pragma unroll
    for (int mf = 0; mf < 2; ++mf) { a0[mf] = ldA(buf, 0, mf); a1[mf] = ldA(buf, 1, mf); }
#pragma unroll
    for (int nf = 0; nf < 2; ++nf) { bq0[nf] = ldB(buf, 0, nf); bq1[nf] = ldB(buf, 1, nf); }
    asm volatile("s_waitcnt lgkmcnt(0)" ::: "memory");
    __builtin_amdgcn_sched_barrier(0);
    __builtin_amdgcn_s_barrier();
    __builtin_amdgcn_sched_barrier(0);
    if (i + 2 < 16) issue3(buf, i + 2);
    __builtin_amdgcn_s_setprio(1);
#pragma unroll
    for (int mf = 0; mf < 2; ++mf)
#pragma unroll
      for (int nf = 0; nf < 2; ++nf) {
        acc[mf][nf] = mfma16(a0[mf], bq0[nf], acc[mf][nf]);
        acc[mf][nf] = mfma16(a1[mf], bq1[nf], acc[mf][nf]);
      }
    __builtin_amdgcn_s_setprio(0);
  }

#pragma unroll
  for (int nf = 0; nf < 2; ++nf) {
    const int n = bn0 + wn * 32 + nf * 16 + ln;
    const float bias = b0[n];
#pragma unroll
    for (int mf = 0; mf < 2; ++mf)
#pragma unroll
      for (int r = 0; r < 4; ++r) {
        const int m = bm0 + wm * 32 + mf * 16 + g * 4 + r;
        outF[(size_t)m * 1024 + n] = acc[mf][nf][r] + bias;
      }
  }
}

// ---------------- flash attention v10 (r13): 12 waves, 3 contiguous kv-groups ----
__global__ __launch_bounds__(768) void attn_k(const unsigned short* __restrict__ qb,
                                              const unsigned short* __restrict__ kb,
                                              const unsigned short* __restrict__ vbT,
                                              unsigned short* __restrict__ ob) {
  extern __shared__ s16x8 kvS[];  // 3 grp x 3 buf x (K 512 | V 512) = 9216 vec = 144KB
  const int t = threadIdx.x;
  const int lane = t & 63, l31 = lane & 31, h5 = lane >> 5;
  const int w = t >> 6, grp = w >> 2, qw = w & 3;  // w 0..11
  const unsigned wg = blockIdx.x;
  const int x = wg & 7, r_ = wg >> 3;
  const int bh = x + 8 * (r_ >> 3);
  const int p = r_ & 7;
  const int b = bh >> 4, h = bh & 15;
  const unsigned short* Qp = qb + (size_t)bh * 131072;
  const unsigned short* Kp = kb + (size_t)bh * 131072;
  const unsigned short* Vp = vbT + (size_t)bh * 131072;

  const int e0 = t & 255;
  const int kr0 = e0 >> 3;
  const int kcol = (e0 & 7) ^ (kr0 & 7);
  const unsigned short* kSrc = Kp + (size_t)kr0 * 64 + kcol * 8;
  const unsigned short* vSrc = Vp + (size_t)kr0 * 2048 + kcol * 8;
  s16x8* gB = &kvS[grp * 3072];

  s16x8 onesv;
#pragma unroll
  for (int z = 0; z < 8; ++z) onesv[z] = (short)0x3F80;  // bf16 1.0
  const bf16x8 onesf = bc8(onesv);

  float* sc = (float*)kvS;
  const int slot = qw * 64 + lane;

  for (int half = 0; half < 2; ++half) {
    const int qblk = half == 0 ? p : 15 - p;
    const int q0 = qblk * 128;
    const int N64 = 2 * qblk + 2;
    const int base = N64 / 3, rem3 = N64 % 3;
    const int cnt = base + (grp < rem3 ? 1 : 0);
    const int start = grp * base + (grp < rem3 ? grp : rem3);
    const int NP = base + (rem3 ? 1 : 0);
    const int qg = q0 + qw * 32 + l31;

    __syncthreads();

    bf16x8 qf[4];
#pragma unroll
    for (int m = 0; m < 4; ++m)
      qf[m] = bc8(*(const s16x8*)(Qp + (size_t)qg * 64 + 16 * m + 8 * h5));

    auto issue = [&](int T, int buf) {
      const int kv0 = T * 64;
      unsigned short* kd = (unsigned short*)&gB[buf * 1024];
      unsigned short* vd = (unsigned short*)&gB[buf * 1024 + 512];
      const unsigned short* ks = kSrc + (size_t)kv0 * 64;
      const unsigned short* vs = vSrc + kv0;
      gl2lds16(ks,         kd + e0 * 8);
      gl2lds16(ks + 2048,  kd + (e0 + 256) * 8);
      gl2lds16(vs,         vd + e0 * 8);
      gl2lds16(vs + 65536, vd + (e0 + 256) * 8);
    };

    if (cnt > 0) issue(start, 0);
    if (cnt > 1) issue(start + 1, 1);

    f32x16 o0 = {}, o1 = {}, lsum = {};

    for (int i = 0; i < NP; ++i) {
      __builtin_amdgcn_sched_barrier(0);
      if (i + 1 < cnt) asm volatile("s_waitcnt vmcnt(4)" ::: "memory");
      else             asm volatile("s_waitcnt vmcnt(0)" ::: "memory");
      __builtin_amdgcn_s_barrier();
      __builtin_amdgcn_sched_barrier(0);
      if (i + 2 < cnt) issue(start + i + 2, (i + 2) % 3);
      const int T = start + i;
      const int kv0 = T * 64;
      const bool active = (i < cnt) && (kv0 <= q0 + qw * 32 + 31);
      if (active) {
        const int buf = i % 3;
        const s16x8* kb_ = &gB[buf * 1024];
        const s16x8* vb2 = &gB[buf * 1024 + 512];
        f32x16 s0 = {}, s1 = {};
        __builtin_amdgcn_s_setprio(1);
#pragma unroll
        for (int m = 0; m < 4; ++m) {
          const int sl = 2 * m + h5;
          bf16x8 a0 = bc8(kb_[l31 * 8 + (sl ^ (l31 & 7))]);
          bf16x8 a1 = bc8(kb_[(l31 + 32) * 8 + (sl ^ (l31 & 7))]);
          s0 = mfma32(a0, qf[m], s0);
          s1 = mfma32(a1, qf[m], s1);
        }
        __builtin_amdgcn_s_setprio(0);
        if (kv0 + 63 > q0 + qw * 32) {
#pragma unroll
          for (int r = 0; r < 16; ++r) {
            const int kvr = kv0 + (r & 3) + 8 * (r >> 2) + 4 * h5;
            if (kvr > qg) s0[r] = -1e30f;
            if (kvr + 32 > qg) s1[r] = -1e30f;
          }
        }
#pragma unroll
        for (int r = 0; r < 16; ++r) {
          s0[r] = __builtin_amdgcn_exp2f(s0[r]);
          s1[r] = __builtin_amdgcn_exp2f(s1[r]);
        }
        unsigned og[2][4][2];
#pragma unroll
        for (int gg = 0; gg < 4; ++gg) {
          asm("v_cvt_pk_bf16_f32 %0, %1, %2" : "=v"(og[0][gg][0]) : "v"(s0[4 * gg]),     "v"(s0[4 * gg + 1]));
          asm("v_cvt_pk_bf16_f32 %0, %1, %2" : "=v"(og[0][gg][1]) : "v"(s0[4 * gg + 2]), "v"(s0[4 * gg + 3]));
          asm("v_cvt_pk_bf16_f32 %0, %1, %2" : "=v"(og[1][gg][0]) : "v"(s1[4 * gg]),     "v"(s1[4 * gg + 1]));
          asm("v_cvt_pk_bf16_f32 %0, %1, %2" : "=v"(og[1][gg][1]) : "v"(s1[4 * gg + 2]), "v"(s1[4 * gg + 3]));
        }
        bf16x8 pf[4];
#pragma unroll
        for (int mp = 0; mp < 4; ++mp) {
          const int tau = mp >> 1, lc = mp & 1;
          unsigned a0 = og[tau][2 * lc][0], bq0 = og[tau][2 * lc + 1][0];
          unsigned a1 = og[tau][2 * lc][1], bq1 = og[tau][2 * lc + 1][1];
          asm volatile("v_permlane32_swap_b32 %0, %1" : "+v"(a0), "+v"(bq0));
          asm volatile("v_permlane32_swap_b32 %0, %1" : "+v"(a1), "+v"(bq1));
          u32x4 fw; fw[0] = a0; fw[1] = a1; fw[2] = bq0; fw[3] = bq1;
          pf[mp] = __builtin_bit_cast(bf16x8, fw);
        }
        __builtin_amdgcn_s_setprio(1);
#pragma unroll
        for (int mp = 0; mp < 4; ++mp) {
          const int sl = 2 * mp + h5;
          bf16x8 va0 = bc8(vb2[l31 * 8 + (sl ^ (l31 & 7))]);
          bf16x8 va1 = bc8(vb2[(l31 + 32) * 8 + (sl ^ (l31 & 7))]);
          o0 = mfma32(va0, pf[mp], o0);
          o1 = mfma32(va1, pf[mp], o1);
          lsum = mfma32(onesf, pf[mp], lsum);
        }
        __builtin_amdgcn_s_setprio(0);
      }
    }

    __syncthreads();
    if (grp > 0) {
      float* dst = sc + (size_t)(grp - 1) * 8704 + (size_t)slot * 34;
#pragma unroll
      for (int r = 0; r < 8; ++r) {
        *(float2*)(dst + 2 * r)      = make_float2(o0[2 * r], o0[2 * r + 1]);
        *(float2*)(dst + 16 + 2 * r) = make_float2(o1[2 * r], o1[2 * r + 1]);
      }
      dst[32] = lsum[0];
    }
    __syncthreads();
    if (grp == 0) {
      const float* p0 = sc + (size_t)slot * 34;
      const float* p1 = p0 + 8704;
      const float inv = 1.0f / (lsum[0] + p0[32] + p1[32]);
      unsigned short* orow = ob + (size_t)(b * 2048 + qg) * 1024 + h * 64;
#pragma unroll
      for (int rq = 0; rq < 4; ++rq) {
        s16x4 ov0, ov1;
#pragma unroll
        for (int e = 0; e < 4; ++e) {
          const int ei = 4 * rq + e;
          ov0[e] = (short)f2bf((o0[ei] + p0[ei] + p1[ei]) * inv);
          ov1[e] = (short)f2bf((o1[ei] + p0[16 + ei] + p1[16 + ei]) * inv);
        }
        *(s16x4*)(orow + 8 * rq + 4 * h5)      = ov0;
        *(s16x4*)(orow + 32 + 8 * rq + 4 * h5) = ov1;
      }
    }
  }
}

extern "C" void kernel_launch(void* const* d_in, const int* in_sizes, int n_in,
                              void* d_out, int out_size, void* d_ws, size_t ws_size,
                              hipStream_t stream) {
  (void)in_sizes; (void)n_in; (void)out_size; (void)ws_size;
  const float* x  = (const float*)d_in[0];
  const float* Wq = (const float*)d_in[1];
  const float* bq = (const float*)d_in[2];
  const float* Wk = (const float*)d_in[3];
  const float* bk = (const float*)d_in[4];
  const float* Wv = (const float*)d_in[5];
  const float* bv = (const float*)d_in[6];
  const float* Wo = (const float*)d_in[7];
  const float* bo = (const float*)d_in[8];
  float* out = (float*)d_out;

  unsigned short* ws  = (unsigned short*)d_ws;
  unsigned short* xb  = ws;
  unsigned short* wtb = ws + 4194304;
  unsigned short* qbuf = ws + 8388608;
  unsigned short* kbuf = qbuf + 4194304;
  unsigned short* vbuf = kbuf + 4194304;   // holds V TRANSPOSED [bh][dh][t]
  unsigned short* ab   = vbuf + 4194304;

  prep_k<<<3072, 256, 0, stream>>>(x, xb, Wq, Wk, Wv, Wo, wtb);
  gemm_qkv_k<<<512, 512, 81920, stream>>>(xb, wtb, bq, bk, bv, out, qbuf, kbuf, vbuf);
  attn_k<<<256, 768, 147456, stream>>>(qbuf, kbuf, vbuf, ab);
  gemm_o_k<<<512, 512, 49152, stream>>>(ab, wtb + 3145728, bo, out);
}